// Round 3
// baseline (206.980 us; speedup 1.0000x reference)
//
#include <hip/hip_runtime.h>
#include <stdint.h>

#define B_ 2
#define S_ 2048
#define E_ 1024
#define H_ 16
#define HD_ 64
#define N_ (B_*S_)
#define BH_ (B_*H_)
#define GAMMA 0.01f

typedef __attribute__((ext_vector_type(8))) short bf16x8;
typedef __attribute__((ext_vector_type(4))) float f32x4;
typedef __attribute__((ext_vector_type(16))) float f32x16;
typedef __attribute__((ext_vector_type(4))) unsigned int u32x4;
typedef unsigned short u16;
typedef unsigned int u32;

// byte-level XOR swizzle within a 128B row: kills stride-128 bank conflicts,
// preserves 16B-chunk contiguity
#define SWZ(row, kb) ((kb) ^ (((row)&7)<<4))

__device__ __forceinline__ u16 f2bf(float f){
  union { float f; u32 u; } v; v.f = f;
  return (u16)((v.u + 0x7FFFu + ((v.u>>16)&1u)) >> 16);
}

__device__ __forceinline__ u32 cvt_pk_bf16(float lo, float hi){
  u32 r; asm("v_cvt_pk_bf16_f32 %0, %1, %2" : "=v"(r) : "v"(lo), "v"(hi)); return r;
}

__device__ __forceinline__ uint4 pack8(float4 a, float4 b){
  uint4 r;
  r.x = (u32)f2bf(a.x) | ((u32)f2bf(a.y)<<16);
  r.y = (u32)f2bf(a.z) | ((u32)f2bf(a.w)<<16);
  r.z = (u32)f2bf(b.x) | ((u32)f2bf(b.y)<<16);
  r.w = (u32)f2bf(b.z) | ((u32)f2bf(b.w)<<16);
  return r;
}

__device__ __forceinline__ bf16x8 ldfrag(const unsigned char* base, int row, int kbyte){
  return *reinterpret_cast<const bf16x8*>(base + row*128 + SWZ(row, kbyte));
}

// ---------------- K0: convert Wo, Wsq fp32 -> bf16 ----------------
__global__ __launch_bounds__(256) void k_cvt(const float* __restrict__ Wo, const float* __restrict__ Wsq,
                                             u16* __restrict__ wo16, u16* __restrict__ wsq16)
{
  int gid = blockIdx.x*256 + threadIdx.x;
  int n4 = (E_*E_)/4;
  const float4* src; ushort4* dst; int i;
  if (gid < n4){ src = (const float4*)Wo;  dst = (ushort4*)wo16;  i = gid; }
  else         { src = (const float4*)Wsq; dst = (ushort4*)wsq16; i = gid - n4; }
  float4 v = src[i];
  ushort4 p; p.x = f2bf(v.x); p.y = f2bf(v.y); p.z = f2bf(v.z); p.w = f2bf(v.w);
  dst[i] = p;
}

// ---------------- K1: per-head QKV projection + xnorm(v), V transposed ----------------
__device__ __forceinline__ void proj_mfma(const unsigned char* X, const unsigned char* W,
                                          int wid, int l15, int g4, f32x4 acc[4])
{
  f32x4 z = {0.f,0.f,0.f,0.f};
  acc[0]=z; acc[1]=z; acc[2]=z; acc[3]=z;
  #pragma unroll
  for (int kk=0;kk<2;++kk){
    int kbyte = kk*64 + g4*16;
    bf16x8 a = ldfrag(X, wid*16 + l15, kbyte);
    #pragma unroll
    for (int t=0;t<4;++t){
      bf16x8 w = ldfrag(W, t*16 + l15, kbyte);
      acc[t] = __builtin_amdgcn_mfma_f32_16x16x32_bf16(a, w, acc[t], 0, 0, 0);
    }
  }
}

__global__ __launch_bounds__(256) void k_proj(
    const float* __restrict__ qin, const float* __restrict__ kin, const float* __restrict__ vin,
    const float* __restrict__ Wq, const float* __restrict__ Wk, const float* __restrict__ Wv,
    u16* __restrict__ qp, u16* __restrict__ kp, u16* __restrict__ vnT)
{
  __shared__ alignas(16) unsigned char sm[57344];
  const int XQ=0, XK=8192, XV=16384, WQS=24576, WKS=32768, WVS=40960, VT=49152;
  int tid = threadIdx.x, lane = tid&63, wid = tid>>6;
  int l15 = lane&15, g4 = lane>>4;
  int tb = blockIdx.x*64;
  int h  = blockIdx.y;
  int b  = tb >> 11;
  int sbase = tb & 2047;
  int bh = b*H_ + h;

  {
    int rl = tid>>2;
    int d0 = (tid&3)*16;
    const float* xs[3] = { qin, kin, vin };
    const float* wsrc[3] = { Wq, Wk, Wv };
    const int xoff[3] = {XQ,XK,XV}, woff[3] = {WQS,WKS,WVS};
    #pragma unroll
    for (int m3=0;m3<3;++m3){
      const float4* gx = reinterpret_cast<const float4*>(xs[m3] + (size_t)(tb+rl)*E_ + h*HD_ + d0);
      float4 a=gx[0], bb=gx[1], c=gx[2], d=gx[3];
      *(uint4*)(sm + xoff[m3] + rl*128 + SWZ(rl, d0*2))    = pack8(a,bb);
      *(uint4*)(sm + xoff[m3] + rl*128 + SWZ(rl, d0*2+16)) = pack8(c,d);
      const float4* gw = reinterpret_cast<const float4*>(wsrc[m3] + rl*64 + d0);
      float4 e=gw[0], f=gw[1], g2=gw[2], h2=gw[3];
      *(uint4*)(sm + woff[m3] + rl*128 + SWZ(rl, d0*2))    = pack8(e,f);
      *(uint4*)(sm + woff[m3] + rl*128 + SWZ(rl, d0*2+16)) = pack8(g2,h2);
    }
  }
  __syncthreads();

  f32x4 acc[4];
  proj_mfma(sm+XQ, sm+WQS, wid, l15, g4, acc);
  #pragma unroll
  for (int t=0;t<4;++t)
    #pragma unroll
    for (int r=0;r<4;++r){
      int tokl = wid*16 + g4*4 + r;
      qp[((size_t)bh*S_ + sbase + tokl)*HD_ + t*16 + l15] = f2bf(acc[t][r]);
    }
  proj_mfma(sm+XK, sm+WKS, wid, l15, g4, acc);
  #pragma unroll
  for (int t=0;t<4;++t)
    #pragma unroll
    for (int r=0;r<4;++r){
      int tokl = wid*16 + g4*4 + r;
      kp[((size_t)bh*S_ + sbase + tokl)*HD_ + t*16 + l15] = f2bf(acc[t][r]);
    }
  proj_mfma(sm+XV, sm+WVS, wid, l15, g4, acc);
  {
    float p4r[4] = {0.f,0.f,0.f,0.f};
    #pragma unroll
    for (int t=0;t<4;++t)
      #pragma unroll
      for (int r=0;r<4;++r){ float e = acc[t][r]; float e2 = e*e; p4r[r] += e2*e2; }
    #pragma unroll
    for (int r=0;r<4;++r){
      float p = p4r[r];
      p += __shfl_xor(p,1); p += __shfl_xor(p,2); p += __shfl_xor(p,4); p += __shfl_xor(p,8);
      p4r[r] = GAMMA / sqrtf(sqrtf(p));
    }
    #pragma unroll
    for (int t=0;t<4;++t)
      #pragma unroll
      for (int r=0;r<4;++r){
        int tokl = wid*16 + g4*4 + r;
        int dd = t*16 + l15;
        *(u16*)(sm + VT + dd*128 + SWZ(dd, tokl*2)) = f2bf(acc[t][r] * p4r[r]);
      }
  }
  __syncthreads();
  {
    int dd = tid>>2; int c2 = tid&3;
    size_t gbase = ((size_t)bh*HD_ + dd)*S_ + sbase + c2*16;
    uint4 v0 = *(const uint4*)(sm + VT + dd*128 + SWZ(dd, c2*32));
    uint4 v1 = *(const uint4*)(sm + VT + dd*128 + SWZ(dd, c2*32+16));
    *(uint4*)(vnT + gbase)     = v0;
    *(uint4*)(vnT + gbase + 8) = v1;
  }
}

// ---------------- K2: flash attention, no-LDS, register-double-buffered fragments ----------------
// Swapped QK^T (A=K rows, B=Q cols) with 32x32x16 MFMA; both K A-frags and V B-frags
// are contiguous 16B/lane global loads (L1 catches the 4x cross-wave reuse per block).
// No __shared__, no barriers; waves pipeline independently.
__global__ __launch_bounds__(256, 2) void k_attn(
    const u16* __restrict__ qp, const u16* __restrict__ kp,
    const u16* __restrict__ vnT, u16* __restrict__ ao)
{
  int tid = threadIdx.x, lane = tid&63, wv = tid>>6;
  int l31 = lane&31, hi = lane>>5;
  // XCD-aware swizzle: xcd L&7 owns bh 4*(L&7)..+3 (2MB K/V working set < 4MB L2/XCD)
  int L = blockIdx.x;
  int xcd = L & 7, iw = L >> 3;
  int bh = xcd*4 + (iw & 3);
  int qx = iw >> 2;                  // 0..15
  int qb = qx*128;
  int b = bh >> 4, h = bh & 15;
  const u16* Kb = kp  + (size_t)bh*S_*HD_;
  const u16* Vb = vnT + (size_t)bh*HD_*S_;
  const u16* Qb = qp  + (size_t)bh*S_*HD_;
  int q0 = qb + wv*32;

  // Q fragments (B-operand): lane holds Q[q=q0+l31][d=kk*16+hi*8 ..+7]
  bf16x8 qf[4];
  #pragma unroll
  for (int kk=0;kk<4;++kk)
    qf[kk] = *reinterpret_cast<const bf16x8*>(Qb + (size_t)(q0+l31)*HD_ + kk*16 + hi*8);

  f32x16 o0 = {}, o1 = {};
  float p4 = 0.f;

  const u16* K0 = Kb + (size_t)l31*HD_      + hi*8;
  const u16* K1 = Kb + (size_t)(32+l31)*HD_ + hi*8;
  const u16* V0 = Vb + (size_t)l31*S_       + hi*8;
  const u16* V1 = Vb + (size_t)(32+l31)*S_  + hi*8;

  bf16x8 kfA[8], vfA[8], kfB[8], vfB[8];   // two named buffers -> static indexing only

  auto LOADT = [&](bf16x8 (&kf)[8], bf16x8 (&vf)[8], int kt){
    size_t kb = (size_t)kt*64;
    #pragma unroll
    for (int kk=0;kk<4;++kk){
      kf[kk*2]   = *reinterpret_cast<const bf16x8*>(K0 + kb*HD_ + kk*16);
      kf[kk*2+1] = *reinterpret_cast<const bf16x8*>(K1 + kb*HD_ + kk*16);
    }
    #pragma unroll
    for (int s=0;s<4;++s){
      vf[s*2]   = *reinterpret_cast<const bf16x8*>(V0 + kb + s*16);
      vf[s*2+1] = *reinterpret_cast<const bf16x8*>(V1 + kb + s*16);
    }
  };

  auto STEP = [&](bf16x8 (&kf)[8], bf16x8 (&vf)[8]){
    // QK^T: e[q=l31][key-reg]
    f32x16 e0 = {}, e1 = {};
    __builtin_amdgcn_s_setprio(1);
    #pragma unroll
    for (int kk=0;kk<4;++kk){
      e0 = __builtin_amdgcn_mfma_f32_32x32x16_bf16(kf[kk*2],   qf[kk], e0, 0,0,0);
      e1 = __builtin_amdgcn_mfma_f32_32x32x16_bf16(kf[kk*2+1], qf[kk], e1, 0,0,0);
    }
    __builtin_amdgcn_s_setprio(0);
    // p4 accumulation + pack E -> bf16 words
    u32 wrd[2][4][2];
    #pragma unroll
    for (int g=0; g<4; ++g)
      #pragma unroll
      for (int i=0;i<2;++i){
        float a0 = e0[4*g+2*i], b0 = e0[4*g+2*i+1];
        float a1 = e1[4*g+2*i], b1 = e1[4*g+2*i+1];
        float a02=a0*a0, b02=b0*b0, a12=a1*a1, b12=b1*b1;
        p4 += a02*a02; p4 += b02*b02; p4 += a12*a12; p4 += b12*b12;
        wrd[0][g][i] = cvt_pk_bf16(a0, b0);
        wrd[1][g][i] = cvt_pk_bf16(a1, b1);
      }
    // PV: A-frag assembly via half-swap; B = V frags from registers
    __builtin_amdgcn_s_setprio(1);
    #pragma unroll
    for (int s=0;s<4;++s){
      const int kb2 = s>>1, sl = s&1;
      u32 send0 = hi ? wrd[kb2][2*sl][0] : wrd[kb2][2*sl+1][0];
      u32 send1 = hi ? wrd[kb2][2*sl][1] : wrd[kb2][2*sl+1][1];
      u32 r0 = (u32)__shfl_xor((int)send0, 32);
      u32 r1 = (u32)__shfl_xor((int)send1, 32);
      u32x4 fw;
      fw.x = hi ? r0 : wrd[kb2][2*sl][0];
      fw.y = hi ? r1 : wrd[kb2][2*sl][1];
      fw.z = hi ? wrd[kb2][2*sl+1][0] : r0;
      fw.w = hi ? wrd[kb2][2*sl+1][1] : r1;
      bf16x8 ef = __builtin_bit_cast(bf16x8, fw);
      o0 = __builtin_amdgcn_mfma_f32_32x32x16_bf16(ef, vf[s*2],   o0, 0,0,0);
      o1 = __builtin_amdgcn_mfma_f32_32x32x16_bf16(ef, vf[s*2+1], o1, 0,0,0);
    }
    __builtin_amdgcn_s_setprio(0);
  };

  LOADT(kfA, vfA, 0);
  #pragma unroll 1
  for (int kt=0; kt<S_/64; kt+=2){
    LOADT(kfB, vfB, kt+1);        // issue next-tile loads, then compute current
    STEP(kfA, vfA);
    if (kt+2 < S_/64) LOADT(kfA, vfA, kt+2);
    STEP(kfB, vfB);
  }

  // epilogue: L4-norm scale + store
  p4 += __shfl_xor(p4, 32);
  float sc_col = GAMMA * rsqrtf(sqrtf(p4));    // gamma * p4^{-1/4} for q = q0 + l31
  #pragma unroll
  for (int r=0;r<16;++r){
    int qrow = (r&3) + 8*(r>>2) + 4*hi;
    float scr = __shfl(sc_col, qrow);
    size_t n = (size_t)b*S_ + qb + wv*32 + qrow;
    u16* dst = ao + n*E_ + h*HD_;
    dst[l31]    = f2bf(o0[r] * scr);
    dst[32+l31] = f2bf(o1[r] * scr);
  }
}

// ---------------- K3/K5: 128x128-tile bf16 GEMM (y = A @ Bw^T) with fused epilogues ----------------
template<int MODE>
__global__ __launch_bounds__(256) void k_gemm(
    const u16* __restrict__ A, const u16* __restrict__ Bw,
    const float* __restrict__ bias, const float* __restrict__ aux,
    float* __restrict__ outp)
{
  __shared__ alignas(16) unsigned char sm[32768];
  const int AS=0, BS=16384;
  int tid = threadIdx.x, lane = tid&63, wid = tid>>6;
  int l15 = lane&15, g4 = lane>>4;
  int m0 = blockIdx.y*128, n0 = blockIdx.x*128;
  int wr = wid>>1, wc = wid&1;
  f32x4 z = {0.f,0.f,0.f,0.f};
  f32x4 acc[4][4];
  #pragma unroll
  for (int i=0;i<4;++i)
    #pragma unroll
    for (int j=0;j<4;++j) acc[i][j] = z;

  int srow = tid>>1, scb4 = (tid&1)*4;
  for (int kt=0; kt<E_/64; ++kt){
    int kb = kt*64;
    const uint4* ga = reinterpret_cast<const uint4*>(A  + (size_t)(m0+srow)*E_ + kb);
    const uint4* gb = reinterpret_cast<const uint4*>(Bw + (size_t)(n0+srow)*E_ + kb);
    #pragma unroll
    for (int i=0;i<4;++i){
      uint4 va = ga[scb4+i];
      *(uint4*)(sm + AS + srow*128 + SWZ(srow, (scb4+i)*16)) = va;
    }
    #pragma unroll
    for (int i=0;i<4;++i){
      uint4 vb = gb[scb4+i];
      *(uint4*)(sm + BS + srow*128 + SWZ(srow, (scb4+i)*16)) = vb;
    }
    __syncthreads();
    #pragma unroll
    for (int kk=0;kk<2;++kk){
      int kbyte = kk*64 + g4*16;
      bf16x8 af[4];
      #pragma unroll
      for (int mi=0;mi<4;++mi) af[mi] = ldfrag(sm+AS, wr*64+mi*16+l15, kbyte);
      #pragma unroll
      for (int ni=0;ni<4;++ni){
        bf16x8 bf = ldfrag(sm+BS, wc*64+ni*16+l15, kbyte);
        #pragma unroll
        for (int mi=0;mi<4;++mi)
          acc[mi][ni] = __builtin_amdgcn_mfma_f32_16x16x32_bf16(af[mi], bf, acc[mi][ni], 0,0,0);
      }
    }
    __syncthreads();
  }
  #pragma unroll
  for (int mi=0;mi<4;++mi)
    #pragma unroll
    for (int ni=0;ni<4;++ni)
      #pragma unroll
      for (int r=0;r<4;++r){
        int row = m0 + wr*64 + mi*16 + g4*4 + r;
        int col = n0 + wc*64 + ni*16 + l15;
        size_t idx = (size_t)row*E_ + col;
        float v = acc[mi][ni][r];
        if (MODE == 0){
          outp[idx] = v + bias[col] + aux[idx];
        } else {
          float zz = v + bias[col];
          float gg = 1.f/(1.f + __expf(-zz));
          outp[idx] = aux[idx] * gg;
        }
      }
}

// ---------------- K4: LayerNorm over embed dim; writes fp32 + bf16 copies ----------------
__global__ __launch_bounds__(256) void k_ln(
    const float* __restrict__ xres, const float* __restrict__ lnw, const float* __restrict__ lnb,
    float* __restrict__ x32, u16* __restrict__ x16)
{
  __shared__ float red[8];
  __shared__ float stats[2];
  int row = blockIdx.x, tid = threadIdx.x;
  float4 x = reinterpret_cast<const float4*>(xres + (size_t)row*E_)[tid];
  float s  = x.x + x.y + x.z + x.w;
  float s2 = x.x*x.x + x.y*x.y + x.z*x.z + x.w*x.w;
  #pragma unroll
  for (int m=1;m<64;m<<=1){ s += __shfl_xor(s,m); s2 += __shfl_xor(s2,m); }
  if ((tid&63)==0){ red[tid>>6] = s; red[4+(tid>>6)] = s2; }
  __syncthreads();
  if (tid==0){
    float ts  = red[0]+red[1]+red[2]+red[3];
    float ts2 = red[4]+red[5]+red[6]+red[7];
    float mu  = ts * (1.f/E_);
    float var = ts2 * (1.f/E_) - mu*mu;
    stats[0] = mu; stats[1] = rsqrtf(var + 1e-5f);
  }
  __syncthreads();
  float mu = stats[0], rstd = stats[1];
  float4 w  = reinterpret_cast<const float4*>(lnw)[tid];
  float4 bb = reinterpret_cast<const float4*>(lnb)[tid];
  float4 y;
  y.x = (x.x-mu)*rstd*w.x + bb.x;
  y.y = (x.y-mu)*rstd*w.y + bb.y;
  y.z = (x.z-mu)*rstd*w.z + bb.z;
  y.w = (x.w-mu)*rstd*w.w + bb.w;
  reinterpret_cast<float4*>(x32 + (size_t)row*E_)[tid] = y;
  ushort4 p; p.x = f2bf(y.x); p.y = f2bf(y.y); p.z = f2bf(y.z); p.w = f2bf(y.w);
  reinterpret_cast<ushort4*>(x16 + (size_t)row*E_)[tid] = p;
}

// ---------------- host launch ----------------
extern "C" void kernel_launch(void* const* d_in, const int* in_sizes, int n_in,
                              void* d_out, int out_size, void* d_ws, size_t ws_size,
                              hipStream_t stream)
{
  const float* value = (const float*)d_in[0];
  const float* key   = (const float*)d_in[1];
  const float* query = (const float*)d_in[2];
  const float* Wq    = (const float*)d_in[3];
  const float* Wk    = (const float*)d_in[4];
  const float* Wv    = (const float*)d_in[5];
  const float* Wo    = (const float*)d_in[6];
  const float* bo    = (const float*)d_in[7];
  const float* lnw   = (const float*)d_in[8];
  const float* lnb   = (const float*)d_in[9];
  const float* Wsq   = (const float*)d_in[10];
  const float* bsq   = (const float*)d_in[11];
  float* out = (float*)d_out;

  char* ws = (char*)d_ws;
  const size_t MB = 1ull<<20;
  u16*   qp    = (u16*)  (ws + 0*MB);
  u16*   kp    = (u16*)  (ws + 8*MB);
  u16*   vnT   = (u16*)  (ws + 16*MB);
  u16*   ao    = (u16*)  (ws + 24*MB);
  float* xres  = (float*)(ws + 8*MB);
  u16*   x16   = (u16*)  (ws + 0*MB);
  float* x32   = (float*)(ws + 32*MB);
  u16*   wo16  = (u16*)  (ws + 48*MB);
  u16*   wsq16 = (u16*)  (ws + 50*MB);

  k_cvt <<<2048, 256, 0, stream>>>(Wo, Wsq, wo16, wsq16);
  k_proj<<<dim3(N_/64, H_), 256, 0, stream>>>(query, key, value, Wq, Wk, Wv, qp, kp, vnT);
  k_attn<<<512, 256, 0, stream>>>(qp, kp, vnT, ao);
  k_gemm<0><<<dim3(E_/128, N_/128), 256, 0, stream>>>(ao, wo16, bo, query, xres);
  k_ln  <<<N_, 256, 0, stream>>>(xres, lnw, lnb, x32, x16);
  k_gemm<1><<<dim3(E_/128, N_/128), 256, 0, stream>>>(x16, wsq16, bsq, x32, out);
}

// Round 4
// 137.320 us; speedup vs baseline: 1.5073x; 1.5073x over previous
//
#include <hip/hip_runtime.h>
#include <stdint.h>

#define B_ 2
#define S_ 2048
#define E_ 1024
#define H_ 16
#define HD_ 64
#define N_ (B_*S_)
#define BH_ (B_*H_)
#define GAMMA 0.01f

typedef __attribute__((ext_vector_type(8))) short bf16x8;
typedef __attribute__((ext_vector_type(4))) float f32x4;
typedef __attribute__((ext_vector_type(16))) float f32x16;
typedef __attribute__((ext_vector_type(4))) unsigned int u32x4;
typedef unsigned short u16;
typedef unsigned int u32;

// byte-level XOR swizzle within a 128B row: kills stride-128 bank conflicts,
// preserves 16B-chunk contiguity
#define SWZ(row, kb) ((kb) ^ (((row)&7)<<4))

__device__ __forceinline__ u16 f2bf(float f){
  union { float f; u32 u; } v; v.f = f;
  return (u16)((v.u + 0x7FFFu + ((v.u>>16)&1u)) >> 16);
}

__device__ __forceinline__ u32 cvt_pk_bf16(float lo, float hi){
  u32 r; asm("v_cvt_pk_bf16_f32 %0, %1, %2" : "=v"(r) : "v"(lo), "v"(hi)); return r;
}

__device__ __forceinline__ uint4 pack8(float4 a, float4 b){
  uint4 r;
  r.x = (u32)f2bf(a.x) | ((u32)f2bf(a.y)<<16);
  r.y = (u32)f2bf(a.z) | ((u32)f2bf(a.w)<<16);
  r.z = (u32)f2bf(b.x) | ((u32)f2bf(b.y)<<16);
  r.w = (u32)f2bf(b.z) | ((u32)f2bf(b.w)<<16);
  return r;
}

__device__ __forceinline__ bf16x8 ldfrag(const unsigned char* base, int row, int kbyte){
  return *reinterpret_cast<const bf16x8*>(base + row*128 + SWZ(row, kbyte));
}

// async global->LDS, 16B per lane; LDS dest = wave-uniform base + lane*16 (linear),
// swizzling achieved by permuting the per-lane SOURCE address (m173 pattern)
__device__ __forceinline__ void gl_lds16(const void* g, void* l){
  __builtin_amdgcn_global_load_lds(
      (const __attribute__((address_space(1))) unsigned int*)g,
      (__attribute__((address_space(3))) unsigned int*)l, 16, 0, 0);
}

// ---------------- K0: convert Wo, Wsq fp32 -> bf16 ----------------
__global__ __launch_bounds__(256) void k_cvt(const float* __restrict__ Wo, const float* __restrict__ Wsq,
                                             u16* __restrict__ wo16, u16* __restrict__ wsq16)
{
  int gid = blockIdx.x*256 + threadIdx.x;
  int n4 = (E_*E_)/4;
  const float4* src; ushort4* dst; int i;
  if (gid < n4){ src = (const float4*)Wo;  dst = (ushort4*)wo16;  i = gid; }
  else         { src = (const float4*)Wsq; dst = (ushort4*)wsq16; i = gid - n4; }
  float4 v = src[i];
  ushort4 p; p.x = f2bf(v.x); p.y = f2bf(v.y); p.z = f2bf(v.z); p.w = f2bf(v.w);
  dst[i] = p;
}

// ---------------- K1: per-head QKV projection + xnorm(v), V transposed ----------------
__device__ __forceinline__ void proj_mfma(const unsigned char* X, const unsigned char* W,
                                          int wid, int l15, int g4, f32x4 acc[4])
{
  f32x4 z = {0.f,0.f,0.f,0.f};
  acc[0]=z; acc[1]=z; acc[2]=z; acc[3]=z;
  #pragma unroll
  for (int kk=0;kk<2;++kk){
    int kbyte = kk*64 + g4*16;
    bf16x8 a = ldfrag(X, wid*16 + l15, kbyte);
    #pragma unroll
    for (int t=0;t<4;++t){
      bf16x8 w = ldfrag(W, t*16 + l15, kbyte);
      acc[t] = __builtin_amdgcn_mfma_f32_16x16x32_bf16(a, w, acc[t], 0, 0, 0);
    }
  }
}

__global__ __launch_bounds__(256) void k_proj(
    const float* __restrict__ qin, const float* __restrict__ kin, const float* __restrict__ vin,
    const float* __restrict__ Wq, const float* __restrict__ Wk, const float* __restrict__ Wv,
    u16* __restrict__ qp, u16* __restrict__ kp, u16* __restrict__ vnT)
{
  __shared__ alignas(16) unsigned char sm[57344];
  const int XQ=0, XK=8192, XV=16384, WQS=24576, WKS=32768, WVS=40960, VT=49152;
  int tid = threadIdx.x, lane = tid&63, wid = tid>>6;
  int l15 = lane&15, g4 = lane>>4;
  int tb = blockIdx.x*64;
  int h  = blockIdx.y;
  int b  = tb >> 11;
  int sbase = tb & 2047;
  int bh = b*H_ + h;

  {
    int rl = tid>>2;
    int d0 = (tid&3)*16;
    const float* xs[3] = { qin, kin, vin };
    const float* wsrc[3] = { Wq, Wk, Wv };
    const int xoff[3] = {XQ,XK,XV}, woff[3] = {WQS,WKS,WVS};
    #pragma unroll
    for (int m3=0;m3<3;++m3){
      const float4* gx = reinterpret_cast<const float4*>(xs[m3] + (size_t)(tb+rl)*E_ + h*HD_ + d0);
      float4 a=gx[0], bb=gx[1], c=gx[2], d=gx[3];
      *(uint4*)(sm + xoff[m3] + rl*128 + SWZ(rl, d0*2))    = pack8(a,bb);
      *(uint4*)(sm + xoff[m3] + rl*128 + SWZ(rl, d0*2+16)) = pack8(c,d);
      const float4* gw = reinterpret_cast<const float4*>(wsrc[m3] + rl*64 + d0);
      float4 e=gw[0], f=gw[1], g2=gw[2], h2=gw[3];
      *(uint4*)(sm + woff[m3] + rl*128 + SWZ(rl, d0*2))    = pack8(e,f);
      *(uint4*)(sm + woff[m3] + rl*128 + SWZ(rl, d0*2+16)) = pack8(g2,h2);
    }
  }
  __syncthreads();

  f32x4 acc[4];
  proj_mfma(sm+XQ, sm+WQS, wid, l15, g4, acc);
  #pragma unroll
  for (int t=0;t<4;++t)
    #pragma unroll
    for (int r=0;r<4;++r){
      int tokl = wid*16 + g4*4 + r;
      qp[((size_t)bh*S_ + sbase + tokl)*HD_ + t*16 + l15] = f2bf(acc[t][r]);
    }
  proj_mfma(sm+XK, sm+WKS, wid, l15, g4, acc);
  #pragma unroll
  for (int t=0;t<4;++t)
    #pragma unroll
    for (int r=0;r<4;++r){
      int tokl = wid*16 + g4*4 + r;
      kp[((size_t)bh*S_ + sbase + tokl)*HD_ + t*16 + l15] = f2bf(acc[t][r]);
    }
  proj_mfma(sm+XV, sm+WVS, wid, l15, g4, acc);
  {
    float p4r[4] = {0.f,0.f,0.f,0.f};
    #pragma unroll
    for (int t=0;t<4;++t)
      #pragma unroll
      for (int r=0;r<4;++r){ float e = acc[t][r]; float e2 = e*e; p4r[r] += e2*e2; }
    #pragma unroll
    for (int r=0;r<4;++r){
      float p = p4r[r];
      p += __shfl_xor(p,1); p += __shfl_xor(p,2); p += __shfl_xor(p,4); p += __shfl_xor(p,8);
      p4r[r] = GAMMA / sqrtf(sqrtf(p));
    }
    #pragma unroll
    for (int t=0;t<4;++t)
      #pragma unroll
      for (int r=0;r<4;++r){
        int tokl = wid*16 + g4*4 + r;
        int dd = t*16 + l15;
        *(u16*)(sm + VT + dd*128 + SWZ(dd, tokl*2)) = f2bf(acc[t][r] * p4r[r]);
      }
  }
  __syncthreads();
  {
    int dd = tid>>2; int c2 = tid&3;
    size_t gbase = ((size_t)bh*HD_ + dd)*S_ + sbase + c2*16;
    uint4 v0 = *(const uint4*)(sm + VT + dd*128 + SWZ(dd, c2*32));
    uint4 v1 = *(const uint4*)(sm + VT + dd*128 + SWZ(dd, c2*32+16));
    *(uint4*)(vnT + gbase)     = v0;
    *(uint4*)(vnT + gbase + 8) = v1;
  }
}

// ---------------- K2: flash attention, 2q x 2k wave split, gl_lds + counted vmcnt ----------------
// Block: 64 q-rows, 4 waves = (2 q-sub) x (2 key-sub). Each wave reads only its
// 32-key half of K and V from LDS (halves LDS-pipe traffic). K/V staged by
// global_load_lds (16B) double-buffered, vmcnt(4) counted waits, raw s_barrier.
__global__ __launch_bounds__(256, 4) void k_attn(
    const u16* __restrict__ qp, const u16* __restrict__ kp,
    const u16* __restrict__ vnT, u16* __restrict__ ao)
{
  __shared__ alignas(128) unsigned char sm[32768];   // 2 x (K 8KB + V 8KB)
  int tid = threadIdx.x, lane = tid&63, wv = tid>>6;
  int l31 = lane&31, hi = lane>>5;
  int qi = wv>>1, kj = wv&1;
  // XCD swizzle: xcd L&7 owns bh 4..7 per XCD -> 2MB K/V + 1MB Q < 4MB L2
  int L = blockIdx.x;
  int xcd = L&7, iw = L>>3;            // iw 0..127
  int bh = xcd*4 + (iw&3);
  int qx = iw>>2;                      // 0..31
  int qb = qx*64;
  int b = bh>>4, h = bh&15;
  const u16* Kb = kp  + (size_t)bh*S_*HD_;
  const u16* Vb = vnT + (size_t)bh*HD_*S_;
  const u16* Qb = qp  + (size_t)bh*S_*HD_;
  int q0 = qb + qi*32;

  // Q fragments (B-operand of 32x32x16): lane holds Q[q=q0+l31][d=kk*16+hi*8 ..+7]
  bf16x8 qf[4];
  #pragma unroll
  for (int kk=0;kk<4;++kk)
    qf[kk] = *reinterpret_cast<const bf16x8*>(Qb + (size_t)(q0+l31)*HD_ + kk*16 + hi*8);

  // staging: wave wv covers LDS rows wv*16..+15 (2 calls of 1KB each for K, same for V).
  // LDS linear layout [64][128]; source col pre-XOR'd so reads can use SWZ().
  int off0 = wv*2048 + lane*16;
  int row0 = off0 >> 7, col0 = (off0 & 127) ^ ((row0 & 7) << 4);
  int off1 = off0 + 1024;
  int row1 = off1 >> 7, col1 = (off1 & 127) ^ ((row1 & 7) << 4);
  const char* kSrc0 = (const char*)Kb + row0*128 + col0;
  const char* kSrc1 = (const char*)Kb + row1*128 + col1;
  const char* vSrc0 = (const char*)Vb + (size_t)row0*4096 + col0;
  const char* vSrc1 = (const char*)Vb + (size_t)row1*4096 + col1;
  char* smc = (char*)sm;
  unsigned dOfs = wv*2048;

  auto STAGE = [&](int bsel, int kt){
    char* db = smc + bsel*16384 + dOfs;
    gl_lds16(kSrc0 + (size_t)kt*8192, db);
    gl_lds16(kSrc1 + (size_t)kt*8192, db + 1024);
    gl_lds16(vSrc0 + (size_t)kt*128,  db + 8192);
    gl_lds16(vSrc1 + (size_t)kt*128,  db + 8192 + 1024);
  };

  f32x16 o0 = {}, o1 = {};
  float p4 = 0.f;

  STAGE(0, 0); STAGE(1, 1);

  #pragma unroll 1
  for (int kt=0; kt<S_/64; ++kt){
    if (kt < S_/64 - 1) { asm volatile("s_waitcnt vmcnt(4)" ::: "memory"); }
    else                { asm volatile("s_waitcnt vmcnt(0)" ::: "memory"); }
    __builtin_amdgcn_s_barrier();
    asm volatile("" ::: "memory");
    const unsigned char* K_ = sm + (kt&1)*16384;
    const unsigned char* V_ = K_ + 8192;

    // ---- QK^T (swapped): A = K rows (our 32-key half), B = Q ----
    f32x16 e = {};
    __builtin_amdgcn_s_setprio(1);
    #pragma unroll
    for (int kk=0;kk<4;++kk){
      bf16x8 ka = ldfrag(K_, kj*32 + l31, kk*32 + hi*16);
      e = __builtin_amdgcn_mfma_f32_32x32x16_bf16(ka, qf[kk], e, 0,0,0);
    }
    __builtin_amdgcn_s_setprio(0);

    // ---- p4 + pack E -> bf16 words; wrd[g][i] = keys {8g+4hi+2i, +1} (local) ----
    u32 wrd[4][2];
    #pragma unroll
    for (int g=0;g<4;++g)
      #pragma unroll
      for (int i=0;i<2;++i){
        float a = e[4*g+2*i], c = e[4*g+2*i+1];
        float a2=a*a, c2=c*c;
        p4 += a2*a2; p4 += c2*c2;
        wrd[g][i] = cvt_pk_bf16(a, c);
      }

    // ---- PV: A-frag via half-swap; B = V^T (our 32-key half) ----
    __builtin_amdgcn_s_setprio(1);
    #pragma unroll
    for (int s=0;s<2;++s){
      u32 send0 = hi ? wrd[2*s][0] : wrd[2*s+1][0];
      u32 send1 = hi ? wrd[2*s][1] : wrd[2*s+1][1];
      u32 r0 = (u32)__shfl_xor((int)send0, 32);
      u32 r1 = (u32)__shfl_xor((int)send1, 32);
      u32x4 fw;
      fw.x = hi ? r0 : wrd[2*s][0];
      fw.y = hi ? r1 : wrd[2*s][1];
      fw.z = hi ? wrd[2*s+1][0] : r0;
      fw.w = hi ? wrd[2*s+1][1] : r1;
      bf16x8 ef = __builtin_bit_cast(bf16x8, fw);
      bf16x8 vb0 = ldfrag(V_, l31,    kj*64 + s*32 + hi*16);
      bf16x8 vb1 = ldfrag(V_, 32+l31, kj*64 + s*32 + hi*16);
      o0 = __builtin_amdgcn_mfma_f32_32x32x16_bf16(ef, vb0, o0, 0,0,0);
      o1 = __builtin_amdgcn_mfma_f32_32x32x16_bf16(ef, vb1, o1, 0,0,0);
    }
    __builtin_amdgcn_s_setprio(0);

    asm volatile("" ::: "memory");
    __builtin_amdgcn_s_barrier();      // all waves done reading buf[kt&1]
    asm volatile("" ::: "memory");
    if (kt+2 < S_/64) STAGE(kt&1, kt+2);
  }

  // ---- cross-wave (key-half) reduce of o and p4, then scale + store ----
  int slot = qi*64 + lane;             // 0..127
  float* redp = (float*)(smc + 16384);
  if (kj==1){
    #pragma unroll
    for (int r4=0;r4<4;++r4){
      float4 t0 = make_float4(o0[r4*4],o0[r4*4+1],o0[r4*4+2],o0[r4*4+3]);
      float4 t1 = make_float4(o1[r4*4],o1[r4*4+1],o1[r4*4+2],o1[r4*4+3]);
      *(float4*)(smc + slot*128 + SWZ(slot, r4*16))      = t0;
      *(float4*)(smc + slot*128 + SWZ(slot, 64 + r4*16)) = t1;
    }
    redp[slot] = p4;
  }
  __syncthreads();
  if (kj==0){
    #pragma unroll
    for (int r4=0;r4<4;++r4){
      float4 t0 = *(const float4*)(smc + slot*128 + SWZ(slot, r4*16));
      float4 t1 = *(const float4*)(smc + slot*128 + SWZ(slot, 64 + r4*16));
      o0[r4*4]+=t0.x; o0[r4*4+1]+=t0.y; o0[r4*4+2]+=t0.z; o0[r4*4+3]+=t0.w;
      o1[r4*4]+=t1.x; o1[r4*4+1]+=t1.y; o1[r4*4+2]+=t1.z; o1[r4*4+3]+=t1.w;
    }
    p4 += redp[slot];
    p4 += __shfl_xor(p4, 32);
    float sc_col = GAMMA * rsqrtf(sqrtf(p4));    // gamma * p4^{-1/4} for q = q0+l31
    #pragma unroll
    for (int r=0;r<16;++r){
      int qrow = (r&3) + 8*(r>>2) + 4*hi;
      float scr = __shfl(sc_col, qrow);
      size_t n = (size_t)b*S_ + qb + qi*32 + qrow;
      u16* dst = ao + n*E_ + h*HD_;
      dst[l31]    = f2bf(o0[r] * scr);
      dst[32+l31] = f2bf(o1[r] * scr);
    }
  }
}

// ---------------- K3/K5: 128x128-tile bf16 GEMM (y = A @ Bw^T) with fused epilogues ----------------
template<int MODE>
__global__ __launch_bounds__(256) void k_gemm(
    const u16* __restrict__ A, const u16* __restrict__ Bw,
    const float* __restrict__ bias, const float* __restrict__ aux,
    float* __restrict__ outp)
{
  __shared__ alignas(16) unsigned char sm[32768];
  const int AS=0, BS=16384;
  int tid = threadIdx.x, lane = tid&63, wid = tid>>6;
  int l15 = lane&15, g4 = lane>>4;
  int m0 = blockIdx.y*128, n0 = blockIdx.x*128;
  int wr = wid>>1, wc = wid&1;
  f32x4 z = {0.f,0.f,0.f,0.f};
  f32x4 acc[4][4];
  #pragma unroll
  for (int i=0;i<4;++i)
    #pragma unroll
    for (int j=0;j<4;++j) acc[i][j] = z;

  int srow = tid>>1, scb4 = (tid&1)*4;
  for (int kt=0; kt<E_/64; ++kt){
    int kb = kt*64;
    const uint4* ga = reinterpret_cast<const uint4*>(A  + (size_t)(m0+srow)*E_ + kb);
    const uint4* gb = reinterpret_cast<const uint4*>(Bw + (size_t)(n0+srow)*E_ + kb);
    #pragma unroll
    for (int i=0;i<4;++i){
      uint4 va = ga[scb4+i];
      *(uint4*)(sm + AS + srow*128 + SWZ(srow, (scb4+i)*16)) = va;
    }
    #pragma unroll
    for (int i=0;i<4;++i){
      uint4 vb = gb[scb4+i];
      *(uint4*)(sm + BS + srow*128 + SWZ(srow, (scb4+i)*16)) = vb;
    }
    __syncthreads();
    #pragma unroll
    for (int kk=0;kk<2;++kk){
      int kbyte = kk*64 + g4*16;
      bf16x8 af[4];
      #pragma unroll
      for (int mi=0;mi<4;++mi) af[mi] = ldfrag(sm+AS, wr*64+mi*16+l15, kbyte);
      #pragma unroll
      for (int ni=0;ni<4;++ni){
        bf16x8 bf = ldfrag(sm+BS, wc*64+ni*16+l15, kbyte);
        #pragma unroll
        for (int mi=0;mi<4;++mi)
          acc[mi][ni] = __builtin_amdgcn_mfma_f32_16x16x32_bf16(af[mi], bf, acc[mi][ni], 0,0,0);
      }
    }
    __syncthreads();
  }
  #pragma unroll
  for (int mi=0;mi<4;++mi)
    #pragma unroll
    for (int ni=0;ni<4;++ni)
      #pragma unroll
      for (int r=0;r<4;++r){
        int row = m0 + wr*64 + mi*16 + g4*4 + r;
        int col = n0 + wc*64 + ni*16 + l15;
        size_t idx = (size_t)row*E_ + col;
        float v = acc[mi][ni][r];
        if (MODE == 0){
          outp[idx] = v + bias[col] + aux[idx];
        } else {
          float zz = v + bias[col];
          float gg = 1.f/(1.f + __expf(-zz));
          outp[idx] = aux[idx] * gg;
        }
      }
}

// ---------------- K4: LayerNorm over embed dim; writes fp32 + bf16 copies ----------------
__global__ __launch_bounds__(256) void k_ln(
    const float* __restrict__ xres, const float* __restrict__ lnw, const float* __restrict__ lnb,
    float* __restrict__ x32, u16* __restrict__ x16)
{
  __shared__ float red[8];
  __shared__ float stats[2];
  int row = blockIdx.x, tid = threadIdx.x;
  float4 x = reinterpret_cast<const float4*>(xres + (size_t)row*E_)[tid];
  float s  = x.x + x.y + x.z + x.w;
  float s2 = x.x*x.x + x.y*x.y + x.z*x.z + x.w*x.w;
  #pragma unroll
  for (int m=1;m<64;m<<=1){ s += __shfl_xor(s,m); s2 += __shfl_xor(s2,m); }
  if ((tid&63)==0){ red[tid>>6] = s; red[4+(tid>>6)] = s2; }
  __syncthreads();
  if (tid==0){
    float ts  = red[0]+red[1]+red[2]+red[3];
    float ts2 = red[4]+red[5]+red[6]+red[7];
    float mu  = ts * (1.f/E_);
    float var = ts2 * (1.f/E_) - mu*mu;
    stats[0] = mu; stats[1] = rsqrtf(var + 1e-5f);
  }
  __syncthreads();
  float mu = stats[0], rstd = stats[1];
  float4 w  = reinterpret_cast<const float4*>(lnw)[tid];
  float4 bb = reinterpret_cast<const float4*>(lnb)[tid];
  float4 y;
  y.x = (x.x-mu)*rstd*w.x + bb.x;
  y.y = (x.y-mu)*rstd*w.y + bb.y;
  y.z = (x.z-mu)*rstd*w.z + bb.z;
  y.w = (x.w-mu)*rstd*w.w + bb.w;
  reinterpret_cast<float4*>(x32 + (size_t)row*E_)[tid] = y;
  ushort4 p; p.x = f2bf(y.x); p.y = f2bf(y.y); p.z = f2bf(y.z); p.w = f2bf(y.w);
  reinterpret_cast<ushort4*>(x16 + (size_t)row*E_)[tid] = p;
}

// ---------------- host launch ----------------
extern "C" void kernel_launch(void* const* d_in, const int* in_sizes, int n_in,
                              void* d_out, int out_size, void* d_ws, size_t ws_size,
                              hipStream_t stream)
{
  const float* value = (const float*)d_in[0];
  const float* key   = (const float*)d_in[1];
  const float* query = (const float*)d_in[2];
  const float* Wq    = (const float*)d_in[3];
  const float* Wk    = (const float*)d_in[4];
  const float* Wv    = (const float*)d_in[5];
  const float* Wo    = (const float*)d_in[6];
  const float* bo    = (const float*)d_in[7];
  const float* lnw   = (const float*)d_in[8];
  const float* lnb   = (const float*)d_in[9];
  const float* Wsq   = (const float*)d_in[10];
  const float* bsq   = (const float*)d_in[11];
  float* out = (float*)d_out;

  char* ws = (char*)d_ws;
  const size_t MB = 1ull<<20;
  u16*   qp    = (u16*)  (ws + 0*MB);
  u16*   kp    = (u16*)  (ws + 8*MB);
  u16*   vnT   = (u16*)  (ws + 16*MB);
  u16*   ao    = (u16*)  (ws + 24*MB);
  float* xres  = (float*)(ws + 8*MB);
  u16*   x16   = (u16*)  (ws + 0*MB);
  float* x32   = (float*)(ws + 32*MB);
  u16*   wo16  = (u16*)  (ws + 48*MB);
  u16*   wsq16 = (u16*)  (ws + 50*MB);

  k_cvt <<<2048, 256, 0, stream>>>(Wo, Wsq, wo16, wsq16);
  k_proj<<<dim3(N_/64, H_), 256, 0, stream>>>(query, key, value, Wq, Wk, Wv, qp, kp, vnT);
  k_attn<<<1024, 256, 0, stream>>>(qp, kp, vnT, ao);
  k_gemm<0><<<dim3(E_/128, N_/128), 256, 0, stream>>>(ao, wo16, bo, query, xres);
  k_ln  <<<N_, 256, 0, stream>>>(xres, lnw, lnb, x32, x16);
  k_gemm<1><<<dim3(E_/128, N_/128), 256, 0, stream>>>(x16, wsq16, bsq, x32, out);
}

// Round 5
// 131.673 us; speedup vs baseline: 1.5719x; 1.0429x over previous
//
#include <hip/hip_runtime.h>
#include <stdint.h>

#define B_ 2
#define S_ 2048
#define E_ 1024
#define H_ 16
#define HD_ 64
#define N_ (B_*S_)
#define BH_ (B_*H_)
#define GAMMA 0.01f

typedef __attribute__((ext_vector_type(8))) short bf16x8;
typedef __attribute__((ext_vector_type(4))) float f32x4;
typedef __attribute__((ext_vector_type(2))) float f32x2;
typedef __attribute__((ext_vector_type(16))) float f32x16;
typedef __attribute__((ext_vector_type(4))) unsigned int u32x4;
typedef unsigned short u16;
typedef unsigned int u32;

// byte-level XOR swizzle within a 128B row: kills stride-128 bank conflicts,
// preserves 16B-chunk contiguity
#define SWZ(row, kb) ((kb) ^ (((row)&7)<<4))

__device__ __forceinline__ u16 f2bf(float f){
  union { float f; u32 u; } v; v.f = f;
  return (u16)((v.u + 0x7FFFu + ((v.u>>16)&1u)) >> 16);
}

__device__ __forceinline__ u32 cvt_pk_bf16(float lo, float hi){
  u32 r; asm("v_cvt_pk_bf16_f32 %0, %1, %2" : "=v"(r) : "v"(lo), "v"(hi)); return r;
}

__device__ __forceinline__ uint4 pack8(float4 a, float4 b){
  uint4 r;
  r.x = (u32)f2bf(a.x) | ((u32)f2bf(a.y)<<16);
  r.y = (u32)f2bf(a.z) | ((u32)f2bf(a.w)<<16);
  r.z = (u32)f2bf(b.x) | ((u32)f2bf(b.y)<<16);
  r.w = (u32)f2bf(b.z) | ((u32)f2bf(b.w)<<16);
  return r;
}

__device__ __forceinline__ bf16x8 ldfrag(const unsigned char* base, int row, int kbyte){
  return *reinterpret_cast<const bf16x8*>(base + row*128 + SWZ(row, kbyte));
}

// async global->LDS, 16B per lane; LDS dest = wave-uniform base + lane*16 (linear),
// swizzling achieved by permuting the per-lane SOURCE address (m173 pattern)
__device__ __forceinline__ void gl_lds16(const void* g, void* l){
  __builtin_amdgcn_global_load_lds(
      (const __attribute__((address_space(1))) unsigned int*)g,
      (__attribute__((address_space(3))) unsigned int*)l, 16, 0, 0);
}

// ---------------- K0: convert Wo, Wsq fp32 -> bf16 ----------------
__global__ __launch_bounds__(256) void k_cvt(const float* __restrict__ Wo, const float* __restrict__ Wsq,
                                             u16* __restrict__ wo16, u16* __restrict__ wsq16)
{
  int gid = blockIdx.x*256 + threadIdx.x;
  int n4 = (E_*E_)/4;
  const float4* src; ushort4* dst; int i;
  if (gid < n4){ src = (const float4*)Wo;  dst = (ushort4*)wo16;  i = gid; }
  else         { src = (const float4*)Wsq; dst = (ushort4*)wsq16; i = gid - n4; }
  float4 v = src[i];
  ushort4 p; p.x = f2bf(v.x); p.y = f2bf(v.y); p.z = f2bf(v.z); p.w = f2bf(v.w);
  dst[i] = p;
}

// ---------------- K1: per-head QKV projection + xnorm(v), V transposed ----------------
__device__ __forceinline__ void proj_mfma(const unsigned char* X, const unsigned char* W,
                                          int wid, int l15, int g4, f32x4 acc[4])
{
  f32x4 z = {0.f,0.f,0.f,0.f};
  acc[0]=z; acc[1]=z; acc[2]=z; acc[3]=z;
  #pragma unroll
  for (int kk=0;kk<2;++kk){
    int kbyte = kk*64 + g4*16;
    bf16x8 a = ldfrag(X, wid*16 + l15, kbyte);
    #pragma unroll
    for (int t=0;t<4;++t){
      bf16x8 w = ldfrag(W, t*16 + l15, kbyte);
      acc[t] = __builtin_amdgcn_mfma_f32_16x16x32_bf16(a, w, acc[t], 0, 0, 0);
    }
  }
}

__global__ __launch_bounds__(256) void k_proj(
    const float* __restrict__ qin, const float* __restrict__ kin, const float* __restrict__ vin,
    const float* __restrict__ Wq, const float* __restrict__ Wk, const float* __restrict__ Wv,
    u16* __restrict__ qp, u16* __restrict__ kp, u16* __restrict__ vnT)
{
  __shared__ alignas(16) unsigned char sm[57344];
  const int XQ=0, XK=8192, XV=16384, WQS=24576, WKS=32768, WVS=40960, VT=49152;
  int tid = threadIdx.x, lane = tid&63, wid = tid>>6;
  int l15 = lane&15, g4 = lane>>4;
  int tb = blockIdx.x*64;
  int h  = blockIdx.y;
  int b  = tb >> 11;
  int sbase = tb & 2047;
  int bh = b*H_ + h;

  {
    int rl = tid>>2;
    int d0 = (tid&3)*16;
    const float* xs[3] = { qin, kin, vin };
    const float* wsrc[3] = { Wq, Wk, Wv };
    const int xoff[3] = {XQ,XK,XV}, woff[3] = {WQS,WKS,WVS};
    #pragma unroll
    for (int m3=0;m3<3;++m3){
      const float4* gx = reinterpret_cast<const float4*>(xs[m3] + (size_t)(tb+rl)*E_ + h*HD_ + d0);
      float4 a=gx[0], bb=gx[1], c=gx[2], d=gx[3];
      *(uint4*)(sm + xoff[m3] + rl*128 + SWZ(rl, d0*2))    = pack8(a,bb);
      *(uint4*)(sm + xoff[m3] + rl*128 + SWZ(rl, d0*2+16)) = pack8(c,d);
      const float4* gw = reinterpret_cast<const float4*>(wsrc[m3] + rl*64 + d0);
      float4 e=gw[0], f=gw[1], g2=gw[2], h2=gw[3];
      *(uint4*)(sm + woff[m3] + rl*128 + SWZ(rl, d0*2))    = pack8(e,f);
      *(uint4*)(sm + woff[m3] + rl*128 + SWZ(rl, d0*2+16)) = pack8(g2,h2);
    }
  }
  __syncthreads();

  f32x4 acc[4];
  proj_mfma(sm+XQ, sm+WQS, wid, l15, g4, acc);
  #pragma unroll
  for (int t=0;t<4;++t)
    #pragma unroll
    for (int r=0;r<4;++r){
      int tokl = wid*16 + g4*4 + r;
      qp[((size_t)bh*S_ + sbase + tokl)*HD_ + t*16 + l15] = f2bf(acc[t][r]);
    }
  proj_mfma(sm+XK, sm+WKS, wid, l15, g4, acc);
  #pragma unroll
  for (int t=0;t<4;++t)
    #pragma unroll
    for (int r=0;r<4;++r){
      int tokl = wid*16 + g4*4 + r;
      kp[((size_t)bh*S_ + sbase + tokl)*HD_ + t*16 + l15] = f2bf(acc[t][r]);
    }
  proj_mfma(sm+XV, sm+WVS, wid, l15, g4, acc);
  {
    float p4r[4] = {0.f,0.f,0.f,0.f};
    #pragma unroll
    for (int t=0;t<4;++t)
      #pragma unroll
      for (int r=0;r<4;++r){ float e = acc[t][r]; float e2 = e*e; p4r[r] += e2*e2; }
    #pragma unroll
    for (int r=0;r<4;++r){
      float p = p4r[r];
      p += __shfl_xor(p,1); p += __shfl_xor(p,2); p += __shfl_xor(p,4); p += __shfl_xor(p,8);
      p4r[r] = GAMMA / sqrtf(sqrtf(p));
    }
    #pragma unroll
    for (int t=0;t<4;++t)
      #pragma unroll
      for (int r=0;r<4;++r){
        int tokl = wid*16 + g4*4 + r;
        int dd = t*16 + l15;
        *(u16*)(sm + VT + dd*128 + SWZ(dd, tokl*2)) = f2bf(acc[t][r] * p4r[r]);
      }
  }
  __syncthreads();
  {
    int dd = tid>>2; int c2 = tid&3;
    size_t gbase = ((size_t)bh*HD_ + dd)*S_ + sbase + c2*16;
    uint4 v0 = *(const uint4*)(sm + VT + dd*128 + SWZ(dd, c2*32));
    uint4 v1 = *(const uint4*)(sm + VT + dd*128 + SWZ(dd, c2*32+16));
    *(uint4*)(vnT + gbase)     = v0;
    *(uint4*)(vnT + gbase + 8) = v1;
  }
}

// ---------------- K2: flash attention, Fq=2 per wave, permlane exchange, 3-buf pipeline ----------------
// Block: 128 q-rows, 4 waves = (2 q-sub: 64 rows each) x (2 key-sub: 32 keys each).
// Each wave computes 2 q-frags -> every K/V LDS fragment feeds 2 MFMAs (2:1 MFMA:LDS).
// E half-exchange done with v_permlane32_swap_b32 (no LDS, no cndmask).
// 3 LDS buffers, ONE s_barrier per tile, counted vmcnt(4) with 2-tile slack.
__global__ __launch_bounds__(256, 2) void k_attn(
    const u16* __restrict__ qp, const u16* __restrict__ kp,
    const u16* __restrict__ vnT, u16* __restrict__ ao)
{
  __shared__ alignas(128) unsigned char sm[49152];   // 3 x (K 8KB + V 8KB)
  char* smc = (char*)sm;
  int tid = threadIdx.x, lane = tid&63, wv = tid>>6;
  int l31 = lane&31, hi = lane>>5;
  int qi = wv>>1, kj = wv&1;
  // XCD swizzle: xcd L&7 owns bh 4*(L&7)..+3 (2MB K/V < 4MB L2/XCD)
  int L = blockIdx.x;
  int xcd = L&7, iw = L>>3;            // iw 0..63
  int bh = xcd*4 + (iw&3);
  int qx = iw>>2;                      // 0..15
  int qb = qx*128;
  int b = bh>>4, h = bh&15;
  const u16* Kb = kp  + (size_t)bh*S_*HD_;
  const u16* Vb = vnT + (size_t)bh*HD_*S_;
  const u16* Qb = qp  + (size_t)bh*S_*HD_;
  int q0 = qb + qi*64;

  // Q fragments (B-operand): 2 q-frags of 32 rows each
  bf16x8 qf[2][4];
  #pragma unroll
  for (int f=0;f<2;++f)
    #pragma unroll
    for (int kk=0;kk<4;++kk)
      qf[f][kk] = *reinterpret_cast<const bf16x8*>(Qb + (size_t)(q0 + f*32 + l31)*HD_ + kk*16 + hi*8);

  f32x16 z16 = {};                 // persistent zero seed for QK chains
  f32x16 o[2][2];
  #pragma unroll
  for (int f=0;f<2;++f){ o[f][0] = z16; o[f][1] = z16; }
  f32x2 p4a[2] = {{0.f,0.f},{0.f,0.f}};

  // staging: wave wv covers LDS rows wv*16..+15 (2 gl_lds of 1KB for K, 2 for V)
  int off0 = wv*2048 + lane*16;
  int row0 = off0 >> 7, col0 = (off0 & 127) ^ ((row0 & 7) << 4);
  int off1 = off0 + 1024;
  int row1 = off1 >> 7, col1 = (off1 & 127) ^ ((row1 & 7) << 4);
  const char* kSrc0 = (const char*)Kb + row0*128 + col0;
  const char* kSrc1 = (const char*)Kb + row1*128 + col1;
  const char* vSrc0 = (const char*)Vb + (size_t)row0*4096 + col0;
  const char* vSrc1 = (const char*)Vb + (size_t)row1*4096 + col1;
  unsigned dOfs = wv*2048;

  auto STAGE = [&](int bsel, int kt){
    char* db = smc + bsel*16384 + dOfs;
    gl_lds16(kSrc0 + (size_t)kt*8192, db);
    gl_lds16(kSrc1 + (size_t)kt*8192, db + 1024);
    gl_lds16(vSrc0 + (size_t)kt*128,  db + 8192);
    gl_lds16(vSrc1 + (size_t)kt*128,  db + 8192 + 1024);
  };

  // pack E pair -> bf16 word + accumulate e^4 with packed-f32 math
  auto PACK = [&](const f32x16& e, u32 (&w)[4][2], f32x2& pa){
    #pragma unroll
    for (int j=0;j<8;++j){
      const int g=j>>1, i=j&1;
      float a = e[4*g+2*i], c = e[4*g+2*i+1];
      f32x2 pr = {a, c};
      f32x2 e2;
      asm("v_pk_mul_f32 %0, %1, %1" : "=v"(e2) : "v"(pr));
      asm("v_pk_fma_f32 %0, %1, %1, %0" : "+v"(pa) : "v"(e2));
      w[g][i] = cvt_pk_bf16(a, c);
    }
  };
  // assemble PV A-frag for 16-key slice s via two permlane32 swaps
  auto AFRAG = [&](u32 (&w)[4][2], int s) -> bf16x8 {
    u32 a0 = w[2*s][0], b0 = w[2*s+1][0];
    u32 a1 = w[2*s][1], b1 = w[2*s+1][1];
    asm("v_permlane32_swap_b32 %0, %1" : "+v"(a0), "+v"(b0));
    asm("v_permlane32_swap_b32 %0, %1" : "+v"(a1), "+v"(b1));
    u32x4 fw = {a0, a1, b0, b1};
    return __builtin_bit_cast(bf16x8, fw);
  };

  const int NT = S_/64;   // 32
  STAGE(0, 0); STAGE(1, 1);

  #pragma unroll 1
  for (int kt=0; kt<NT; ++kt){
    if (kt < NT-1) { asm volatile("s_waitcnt vmcnt(4)" ::: "memory"); }
    else           { asm volatile("s_waitcnt vmcnt(0)" ::: "memory"); }
    __builtin_amdgcn_s_barrier();
    asm volatile("" ::: "memory");
    if (kt+2 < NT) STAGE((kt+2)%3, kt+2);   // issue early; lands under compute

    const unsigned char* K_ = sm + (kt%3)*16384;
    const unsigned char* V_ = K_ + 8192;

    // ---- QK^T (swapped): A = K rows (our 32-key half), B = Q; 2 q-frags ----
    bf16x8 ka[4];
    #pragma unroll
    for (int kk=0;kk<4;++kk) ka[kk] = ldfrag(K_, kj*32 + l31, kk*32 + hi*16);
    f32x16 e0 = z16, e1 = z16;
    __builtin_amdgcn_s_setprio(1);
    #pragma unroll
    for (int kk=0;kk<4;++kk){
      e0 = __builtin_amdgcn_mfma_f32_32x32x16_bf16(ka[kk], qf[0][kk], e0, 0,0,0);
      e1 = __builtin_amdgcn_mfma_f32_32x32x16_bf16(ka[kk], qf[1][kk], e1, 0,0,0);
    }
    __builtin_amdgcn_s_setprio(0);

    u32 wrd0[4][2], wrd1[4][2];
    PACK(e0, wrd0, p4a[0]);
    PACK(e1, wrd1, p4a[1]);

    // ---- PV: A-frag via permlane swap; B = V^T (our 32-key half); V reused by both q-frags ----
    #pragma unroll
    for (int s=0;s<2;++s){
      bf16x8 ef0 = AFRAG(wrd0, s);
      bf16x8 ef1 = AFRAG(wrd1, s);
      bf16x8 vb0 = ldfrag(V_, l31,    kj*64 + s*32 + hi*16);
      bf16x8 vb1 = ldfrag(V_, 32+l31, kj*64 + s*32 + hi*16);
      __builtin_amdgcn_s_setprio(1);
      o[0][0] = __builtin_amdgcn_mfma_f32_32x32x16_bf16(ef0, vb0, o[0][0], 0,0,0);
      o[0][1] = __builtin_amdgcn_mfma_f32_32x32x16_bf16(ef0, vb1, o[0][1], 0,0,0);
      o[1][0] = __builtin_amdgcn_mfma_f32_32x32x16_bf16(ef1, vb0, o[1][0], 0,0,0);
      o[1][1] = __builtin_amdgcn_mfma_f32_32x32x16_bf16(ef1, vb1, o[1][1], 0,0,0);
      __builtin_amdgcn_s_setprio(0);
    }
  }

  // ---- cross-wave (key-half) reduce via LDS, then L4 scale + store ----
  float p4f[2];
  #pragma unroll
  for (int f=0;f<2;++f) p4f[f] = p4a[f].x + p4a[f].y;

  __syncthreads();                      // all buffer reads done; reuse sm for reduce
  float* red  = (float*)smc;            // [qi][f][ds][lane][16] = 32KB
  float* redp = (float*)(smc + 32768);  // [qi][f][lane] = 1KB
  if (kj==1){
    #pragma unroll
    for (int f=0;f<2;++f){
      #pragma unroll
      for (int ds=0;ds<2;++ds){
        float* dst = red + ((((qi*2+f)*2+ds)*64 + lane)*16);
        #pragma unroll
        for (int r4=0;r4<4;++r4)
          *(float4*)(dst + r4*4) = make_float4(o[f][ds][r4*4],o[f][ds][r4*4+1],o[f][ds][r4*4+2],o[f][ds][r4*4+3]);
      }
      redp[(qi*2+f)*64 + lane] = p4f[f];
    }
  }
  __syncthreads();
  if (kj==0){
    #pragma unroll
    for (int f=0;f<2;++f){
      #pragma unroll
      for (int ds=0;ds<2;++ds){
        const float* srcp = red + ((((qi*2+f)*2+ds)*64 + lane)*16);
        #pragma unroll
        for (int r4=0;r4<4;++r4){
          float4 t = *(const float4*)(srcp + r4*4);
          o[f][ds][r4*4]+=t.x; o[f][ds][r4*4+1]+=t.y; o[f][ds][r4*4+2]+=t.z; o[f][ds][r4*4+3]+=t.w;
        }
      }
      p4f[f] += redp[(qi*2+f)*64 + lane];
      p4f[f] += __shfl_xor(p4f[f], 32);
    }
    float sc0 = GAMMA * rsqrtf(sqrtf(p4f[0]));
    float sc1 = GAMMA * rsqrtf(sqrtf(p4f[1]));
    #pragma unroll
    for (int f=0;f<2;++f){
      #pragma unroll
      for (int r=0;r<16;++r){
        int qrow = (r&3) + 8*(r>>2) + 4*hi;
        float scr = __shfl(f==0 ? sc0 : sc1, qrow);
        size_t n = (size_t)b*S_ + q0 + f*32 + qrow;
        u16* dst = ao + n*E_ + h*HD_;
        dst[l31]    = f2bf(o[f][0][r] * scr);
        dst[32+l31] = f2bf(o[f][1][r] * scr);
      }
    }
  }
}

// ---------------- K3/K5: 128x128-tile bf16 GEMM (y = A @ Bw^T) with fused epilogues ----------------
template<int MODE>
__global__ __launch_bounds__(256) void k_gemm(
    const u16* __restrict__ A, const u16* __restrict__ Bw,
    const float* __restrict__ bias, const float* __restrict__ aux,
    float* __restrict__ outp)
{
  __shared__ alignas(16) unsigned char sm[32768];
  const int AS=0, BS=16384;
  int tid = threadIdx.x, lane = tid&63, wid = tid>>6;
  int l15 = lane&15, g4 = lane>>4;
  int m0 = blockIdx.y*128, n0 = blockIdx.x*128;
  int wr = wid>>1, wc = wid&1;
  f32x4 z = {0.f,0.f,0.f,0.f};
  f32x4 acc[4][4];
  #pragma unroll
  for (int i=0;i<4;++i)
    #pragma unroll
    for (int j=0;j<4;++j) acc[i][j] = z;

  int srow = tid>>1, scb4 = (tid&1)*4;
  for (int kt=0; kt<E_/64; ++kt){
    int kb = kt*64;
    const uint4* ga = reinterpret_cast<const uint4*>(A  + (size_t)(m0+srow)*E_ + kb);
    const uint4* gb = reinterpret_cast<const uint4*>(Bw + (size_t)(n0+srow)*E_ + kb);
    #pragma unroll
    for (int i=0;i<4;++i){
      uint4 va = ga[scb4+i];
      *(uint4*)(sm + AS + srow*128 + SWZ(srow, (scb4+i)*16)) = va;
    }
    #pragma unroll
    for (int i=0;i<4;++i){
      uint4 vb = gb[scb4+i];
      *(uint4*)(sm + BS + srow*128 + SWZ(srow, (scb4+i)*16)) = vb;
    }
    __syncthreads();
    #pragma unroll
    for (int kk=0;kk<2;++kk){
      int kbyte = kk*64 + g4*16;
      bf16x8 af[4];
      #pragma unroll
      for (int mi=0;mi<4;++mi) af[mi] = ldfrag(sm+AS, wr*64+mi*16+l15, kbyte);
      #pragma unroll
      for (int ni=0;ni<4;++ni){
        bf16x8 bf = ldfrag(sm+BS, wc*64+ni*16+l15, kbyte);
        #pragma unroll
        for (int mi=0;mi<4;++mi)
          acc[mi][ni] = __builtin_amdgcn_mfma_f32_16x16x32_bf16(af[mi], bf, acc[mi][ni], 0,0,0);
      }
    }
    __syncthreads();
  }
  #pragma unroll
  for (int mi=0;mi<4;++mi)
    #pragma unroll
    for (int ni=0;ni<4;++ni)
      #pragma unroll
      for (int r=0;r<4;++r){
        int row = m0 + wr*64 + mi*16 + g4*4 + r;
        int col = n0 + wc*64 + ni*16 + l15;
        size_t idx = (size_t)row*E_ + col;
        float v = acc[mi][ni][r];
        if (MODE == 0){
          outp[idx] = v + bias[col] + aux[idx];
        } else {
          float zz = v + bias[col];
          float gg = 1.f/(1.f + __expf(-zz));
          outp[idx] = aux[idx] * gg;
        }
      }
}

// ---------------- K4: LayerNorm over embed dim; writes fp32 + bf16 copies ----------------
__global__ __launch_bounds__(256) void k_ln(
    const float* __restrict__ xres, const float* __restrict__ lnw, const float* __restrict__ lnb,
    float* __restrict__ x32, u16* __restrict__ x16)
{
  __shared__ float red[8];
  __shared__ float stats[2];
  int row = blockIdx.x, tid = threadIdx.x;
  float4 x = reinterpret_cast<const float4*>(xres + (size_t)row*E_)[tid];
  float s  = x.x + x.y + x.z + x.w;
  float s2 = x.x*x.x + x.y*x.y + x.z*x.z + x.w*x.w;
  #pragma unroll
  for (int m=1;m<64;m<<=1){ s += __shfl_xor(s,m); s2 += __shfl_xor(s2,m); }
  if ((tid&63)==0){ red[tid>>6] = s; red[4+(tid>>6)] = s2; }
  __syncthreads();
  if (tid==0){
    float ts  = red[0]+red[1]+red[2]+red[3];
    float ts2 = red[4]+red[5]+red[6]+red[7];
    float mu  = ts * (1.f/E_);
    float var = ts2 * (1.f/E_) - mu*mu;
    stats[0] = mu; stats[1] = rsqrtf(var + 1e-5f);
  }
  __syncthreads();
  float mu = stats[0], rstd = stats[1];
  float4 w  = reinterpret_cast<const float4*>(lnw)[tid];
  float4 bb = reinterpret_cast<const float4*>(lnb)[tid];
  float4 y;
  y.x = (x.x-mu)*rstd*w.x + bb.x;
  y.y = (x.y-mu)*rstd*w.y + bb.y;
  y.z = (x.z-mu)*rstd*w.z + bb.z;
  y.w = (x.w-mu)*rstd*w.w + bb.w;
  reinterpret_cast<float4*>(x32 + (size_t)row*E_)[tid] = y;
  ushort4 p; p.x = f2bf(y.x); p.y = f2bf(y.y); p.z = f2bf(y.z); p.w = f2bf(y.w);
  reinterpret_cast<ushort4*>(x16 + (size_t)row*E_)[tid] = p;
}

// ---------------- host launch ----------------
extern "C" void kernel_launch(void* const* d_in, const int* in_sizes, int n_in,
                              void* d_out, int out_size, void* d_ws, size_t ws_size,
                              hipStream_t stream)
{
  const float* value = (const float*)d_in[0];
  const float* key   = (const float*)d_in[1];
  const float* query = (const float*)d_in[2];
  const float* Wq    = (const float*)d_in[3];
  const float* Wk    = (const float*)d_in[4];
  const float* Wv    = (const float*)d_in[5];
  const float* Wo    = (const float*)d_in[6];
  const float* bo    = (const float*)d_in[7];
  const float* lnw   = (const float*)d_in[8];
  const float* lnb   = (const float*)d_in[9];
  const float* Wsq   = (const float*)d_in[10];
  const float* bsq   = (const float*)d_in[11];
  float* out = (float*)d_out;

  char* ws = (char*)d_ws;
  const size_t MB = 1ull<<20;
  u16*   qp    = (u16*)  (ws + 0*MB);
  u16*   kp    = (u16*)  (ws + 8*MB);
  u16*   vnT   = (u16*)  (ws + 16*MB);
  u16*   ao    = (u16*)  (ws + 24*MB);
  float* xres  = (float*)(ws + 8*MB);
  u16*   x16   = (u16*)  (ws + 0*MB);
  float* x32   = (float*)(ws + 32*MB);
  u16*   wo16  = (u16*)  (ws + 48*MB);
  u16*   wsq16 = (u16*)  (ws + 50*MB);

  k_cvt <<<2048, 256, 0, stream>>>(Wo, Wsq, wo16, wsq16);
  k_proj<<<dim3(N_/64, H_), 256, 0, stream>>>(query, key, value, Wq, Wk, Wv, qp, kp, vnT);
  k_attn<<<512, 256, 0, stream>>>(qp, kp, vnT, ao);
  k_gemm<0><<<dim3(E_/128, N_/128), 256, 0, stream>>>(ao, wo16, bo, query, xres);
  k_ln  <<<N_, 256, 0, stream>>>(xres, lnw, lnb, x32, x16);
  k_gemm<1><<<dim3(E_/128, N_/128), 256, 0, stream>>>(x16, wsq16, bsq, x32, out);
}

// Round 6
// 131.667 us; speedup vs baseline: 1.5720x; 1.0000x over previous
//
#include <hip/hip_runtime.h>
#include <stdint.h>

#define B_ 2
#define S_ 2048
#define E_ 1024
#define H_ 16
#define HD_ 64
#define N_ (B_*S_)
#define BH_ (B_*H_)
#define GAMMA 0.01f

typedef __attribute__((ext_vector_type(8))) short bf16x8;
typedef __attribute__((ext_vector_type(4))) float f32x4;
typedef __attribute__((ext_vector_type(2))) float f32x2;
typedef __attribute__((ext_vector_type(16))) float f32x16;
typedef __attribute__((ext_vector_type(4))) unsigned int u32x4;
typedef unsigned short u16;
typedef unsigned int u32;

// byte-level XOR swizzle within a 128B row: kills stride-128 bank conflicts,
// preserves 16B-chunk contiguity
#define SWZ(row, kb) ((kb) ^ (((row)&7)<<4))

__device__ __forceinline__ u16 f2bf(float f){
  union { float f; u32 u; } v; v.f = f;
  return (u16)((v.u + 0x7FFFu + ((v.u>>16)&1u)) >> 16);
}

__device__ __forceinline__ u32 cvt_pk_bf16(float lo, float hi){
  u32 r; asm("v_cvt_pk_bf16_f32 %0, %1, %2" : "=v"(r) : "v"(lo), "v"(hi)); return r;
}

__device__ __forceinline__ uint4 pack8(float4 a, float4 b){
  uint4 r;
  r.x = (u32)f2bf(a.x) | ((u32)f2bf(a.y)<<16);
  r.y = (u32)f2bf(a.z) | ((u32)f2bf(a.w)<<16);
  r.z = (u32)f2bf(b.x) | ((u32)f2bf(b.y)<<16);
  r.w = (u32)f2bf(b.z) | ((u32)f2bf(b.w)<<16);
  return r;
}

__device__ __forceinline__ bf16x8 ldfrag(const unsigned char* base, int row, int kbyte){
  return *reinterpret_cast<const bf16x8*>(base + row*128 + SWZ(row, kbyte));
}

// async global->LDS, 16B per lane; LDS dest = wave-uniform base + lane*16 (linear),
// swizzling achieved by permuting the per-lane SOURCE address (m173 pattern)
__device__ __forceinline__ void gl_lds16(const void* g, void* l){
  __builtin_amdgcn_global_load_lds(
      (const __attribute__((address_space(1))) unsigned int*)g,
      (__attribute__((address_space(3))) unsigned int*)l, 16, 0, 0);
}

// ---------------- K0: convert Wo, Wsq fp32 -> bf16 ----------------
__global__ __launch_bounds__(256) void k_cvt(const float* __restrict__ Wo, const float* __restrict__ Wsq,
                                             u16* __restrict__ wo16, u16* __restrict__ wsq16)
{
  int gid = blockIdx.x*256 + threadIdx.x;
  int n4 = (E_*E_)/4;
  const float4* src; ushort4* dst; int i;
  if (gid < n4){ src = (const float4*)Wo;  dst = (ushort4*)wo16;  i = gid; }
  else         { src = (const float4*)Wsq; dst = (ushort4*)wsq16; i = gid - n4; }
  float4 v = src[i];
  ushort4 p; p.x = f2bf(v.x); p.y = f2bf(v.y); p.z = f2bf(v.z); p.w = f2bf(v.w);
  dst[i] = p;
}

// ---------------- K1: per-head QKV projection + xnorm(v), V transposed ----------------
__device__ __forceinline__ void proj_mfma(const unsigned char* X, const unsigned char* W,
                                          int wid, int l15, int g4, f32x4 acc[4])
{
  f32x4 z = {0.f,0.f,0.f,0.f};
  acc[0]=z; acc[1]=z; acc[2]=z; acc[3]=z;
  #pragma unroll
  for (int kk=0;kk<2;++kk){
    int kbyte = kk*64 + g4*16;
    bf16x8 a = ldfrag(X, wid*16 + l15, kbyte);
    #pragma unroll
    for (int t=0;t<4;++t){
      bf16x8 w = ldfrag(W, t*16 + l15, kbyte);
      acc[t] = __builtin_amdgcn_mfma_f32_16x16x32_bf16(a, w, acc[t], 0, 0, 0);
    }
  }
}

__global__ __launch_bounds__(256) void k_proj(
    const float* __restrict__ qin, const float* __restrict__ kin, const float* __restrict__ vin,
    const float* __restrict__ Wq, const float* __restrict__ Wk, const float* __restrict__ Wv,
    u16* __restrict__ qp, u16* __restrict__ kp, u16* __restrict__ vnT)
{
  __shared__ alignas(16) unsigned char sm[57344];
  const int XQ=0, XK=8192, XV=16384, WQS=24576, WKS=32768, WVS=40960, VT=49152;
  int tid = threadIdx.x, lane = tid&63, wid = tid>>6;
  int l15 = lane&15, g4 = lane>>4;
  int tb = blockIdx.x*64;
  int h  = blockIdx.y;
  int b  = tb >> 11;
  int sbase = tb & 2047;
  int bh = b*H_ + h;

  {
    int rl = tid>>2;
    int d0 = (tid&3)*16;
    const float* xs[3] = { qin, kin, vin };
    const float* wsrc[3] = { Wq, Wk, Wv };
    const int xoff[3] = {XQ,XK,XV}, woff[3] = {WQS,WKS,WVS};
    #pragma unroll
    for (int m3=0;m3<3;++m3){
      const float4* gx = reinterpret_cast<const float4*>(xs[m3] + (size_t)(tb+rl)*E_ + h*HD_ + d0);
      float4 a=gx[0], bb=gx[1], c=gx[2], d=gx[3];
      *(uint4*)(sm + xoff[m3] + rl*128 + SWZ(rl, d0*2))    = pack8(a,bb);
      *(uint4*)(sm + xoff[m3] + rl*128 + SWZ(rl, d0*2+16)) = pack8(c,d);
      const float4* gw = reinterpret_cast<const float4*>(wsrc[m3] + rl*64 + d0);
      float4 e=gw[0], f=gw[1], g2=gw[2], h2=gw[3];
      *(uint4*)(sm + woff[m3] + rl*128 + SWZ(rl, d0*2))    = pack8(e,f);
      *(uint4*)(sm + woff[m3] + rl*128 + SWZ(rl, d0*2+16)) = pack8(g2,h2);
    }
  }
  __syncthreads();

  f32x4 acc[4];
  proj_mfma(sm+XQ, sm+WQS, wid, l15, g4, acc);
  #pragma unroll
  for (int t=0;t<4;++t)
    #pragma unroll
    for (int r=0;r<4;++r){
      int tokl = wid*16 + g4*4 + r;
      qp[((size_t)bh*S_ + sbase + tokl)*HD_ + t*16 + l15] = f2bf(acc[t][r]);
    }
  proj_mfma(sm+XK, sm+WKS, wid, l15, g4, acc);
  #pragma unroll
  for (int t=0;t<4;++t)
    #pragma unroll
    for (int r=0;r<4;++r){
      int tokl = wid*16 + g4*4 + r;
      kp[((size_t)bh*S_ + sbase + tokl)*HD_ + t*16 + l15] = f2bf(acc[t][r]);
    }
  proj_mfma(sm+XV, sm+WVS, wid, l15, g4, acc);
  {
    float p4r[4] = {0.f,0.f,0.f,0.f};
    #pragma unroll
    for (int t=0;t<4;++t)
      #pragma unroll
      for (int r=0;r<4;++r){ float e = acc[t][r]; float e2 = e*e; p4r[r] += e2*e2; }
    #pragma unroll
    for (int r=0;r<4;++r){
      float p = p4r[r];
      p += __shfl_xor(p,1); p += __shfl_xor(p,2); p += __shfl_xor(p,4); p += __shfl_xor(p,8);
      p4r[r] = GAMMA / sqrtf(sqrtf(p));
    }
    #pragma unroll
    for (int t=0;t<4;++t)
      #pragma unroll
      for (int r=0;r<4;++r){
        int tokl = wid*16 + g4*4 + r;
        int dd = t*16 + l15;
        *(u16*)(sm + VT + dd*128 + SWZ(dd, tokl*2)) = f2bf(acc[t][r] * p4r[r]);
      }
  }
  __syncthreads();
  {
    int dd = tid>>2; int c2 = tid&3;
    size_t gbase = ((size_t)bh*HD_ + dd)*S_ + sbase + c2*16;
    uint4 v0 = *(const uint4*)(sm + VT + dd*128 + SWZ(dd, c2*32));
    uint4 v1 = *(const uint4*)(sm + VT + dd*128 + SWZ(dd, c2*32+16));
    *(uint4*)(vnT + gbase)     = v0;
    *(uint4*)(vnT + gbase + 8) = v1;
  }
}

// ---------------- K2: flash attention, Fq=2, cross-tile software pipeline (T15) ----------------
// Block: 128 q-rows, 4 waves = (2 q-sub: 64 rows) x (2 key-sub: 32 keys).
// Two e-accumulator sets (eA/eB, 2-step unrolled loop -> static indexing): QK(t+1)
// issues right after the barrier, a full PACK+PV region before its results are
// consumed; PV(t) MFMAs execute during the barrier drain. 3 LDS buffers, one
// barrier/tile, counted vmcnt(4), stage lands ~1.5 tiles ahead.
__global__ __launch_bounds__(256, 2) void k_attn(
    const u16* __restrict__ qp, const u16* __restrict__ kp,
    const u16* __restrict__ vnT, u16* __restrict__ ao)
{
  __shared__ alignas(128) unsigned char sm[49152];   // 3 x (K 8KB + V 8KB)
  char* smc = (char*)sm;
  int tid = threadIdx.x, lane = tid&63, wv = tid>>6;
  int l31 = lane&31, hi = lane>>5;
  int qi = wv>>1, kj = wv&1;
  int L = blockIdx.x;
  int xcd = L&7, iw = L>>3;            // iw 0..63
  int bh = xcd*4 + (iw&3);
  int qx = iw>>2;                      // 0..15
  int qb = qx*128;
  int b = bh>>4, h = bh&15;
  const u16* Kb = kp  + (size_t)bh*S_*HD_;
  const u16* Vb = vnT + (size_t)bh*HD_*S_;
  const u16* Qb = qp  + (size_t)bh*S_*HD_;
  int q0 = qb + qi*64;

  // Q fragments (B-operand): 2 q-frags of 32 rows each
  bf16x8 qf[2][4];
  #pragma unroll
  for (int f=0;f<2;++f)
    #pragma unroll
    for (int kk=0;kk<4;++kk)
      qf[f][kk] = *reinterpret_cast<const bf16x8*>(Qb + (size_t)(q0 + f*32 + l31)*HD_ + kk*16 + hi*8);

  f32x16 z16 = {};
  f32x16 o[2][2];
  #pragma unroll
  for (int f=0;f<2;++f){ o[f][0] = z16; o[f][1] = z16; }
  f32x2 p4a[2] = {{0.f,0.f},{0.f,0.f}};

  // staging: wave wv covers LDS rows wv*16..+15; source col pre-XOR'd (m173)
  int off0 = wv*2048 + lane*16;
  int row0 = off0 >> 7, col0 = (off0 & 127) ^ ((row0 & 7) << 4);
  int off1 = off0 + 1024;
  int row1 = off1 >> 7, col1 = (off1 & 127) ^ ((row1 & 7) << 4);
  const char* kSrc0 = (const char*)Kb + row0*128 + col0;
  const char* kSrc1 = (const char*)Kb + row1*128 + col1;
  const char* vSrc0 = (const char*)Vb + (size_t)row0*4096 + col0;
  const char* vSrc1 = (const char*)Vb + (size_t)row1*4096 + col1;
  unsigned dOfs = wv*2048;

  auto STAGE = [&](int bsel, int kt){
    char* db = smc + bsel*16384 + dOfs;
    gl_lds16(kSrc0 + (size_t)kt*8192, db);
    gl_lds16(kSrc1 + (size_t)kt*8192, db + 1024);
    gl_lds16(vSrc0 + (size_t)kt*128,  db + 8192);
    gl_lds16(vSrc1 + (size_t)kt*128,  db + 8192 + 1024);
  };

  auto PACK = [&](const f32x16& e, u32 (&w)[4][2], f32x2& pa){
    #pragma unroll
    for (int j=0;j<8;++j){
      const int g=j>>1, i=j&1;
      float a = e[4*g+2*i], c = e[4*g+2*i+1];
      f32x2 pr = {a, c};
      f32x2 e2;
      asm("v_pk_mul_f32 %0, %1, %1" : "=v"(e2) : "v"(pr));
      asm("v_pk_fma_f32 %0, %1, %1, %0" : "+v"(pa) : "v"(e2));
      w[g][i] = cvt_pk_bf16(a, c);
    }
  };
  auto AFRAG = [&](u32 (&w)[4][2], int s) -> bf16x8 {
    u32 a0 = w[2*s][0], b0 = w[2*s+1][0];
    u32 a1 = w[2*s][1], b1 = w[2*s+1][1];
    asm("v_permlane32_swap_b32 %0, %1" : "+v"(a0), "+v"(b0));
    asm("v_permlane32_swap_b32 %0, %1" : "+v"(a1), "+v"(b1));
    u32x4 fw = {a0, a1, b0, b1};
    return __builtin_bit_cast(bf16x8, fw);
  };

  auto QK = [&](const unsigned char* K_, f32x16& E0, f32x16& E1){
    bf16x8 ka[4];
    #pragma unroll
    for (int kk=0;kk<4;++kk) ka[kk] = ldfrag(K_, kj*32 + l31, kk*32 + hi*16);
    E0 = z16; E1 = z16;
    __builtin_amdgcn_s_setprio(1);
    #pragma unroll
    for (int kk=0;kk<4;++kk){
      E0 = __builtin_amdgcn_mfma_f32_32x32x16_bf16(ka[kk], qf[0][kk], E0, 0,0,0);
      E1 = __builtin_amdgcn_mfma_f32_32x32x16_bf16(ka[kk], qf[1][kk], E1, 0,0,0);
    }
    __builtin_amdgcn_s_setprio(0);
  };

  auto PVF = [&](const unsigned char* V_, u32 (&w0)[4][2], u32 (&w1)[4][2]){
    bf16x8 vb[2][2];
    #pragma unroll
    for (int s=0;s<2;++s){
      vb[s][0] = ldfrag(V_, l31,    kj*64 + s*32 + hi*16);
      vb[s][1] = ldfrag(V_, 32+l31, kj*64 + s*32 + hi*16);
    }
    __builtin_amdgcn_s_setprio(1);
    #pragma unroll
    for (int s=0;s<2;++s){
      bf16x8 ef0 = AFRAG(w0, s);
      bf16x8 ef1 = AFRAG(w1, s);
      o[0][0] = __builtin_amdgcn_mfma_f32_32x32x16_bf16(ef0, vb[s][0], o[0][0], 0,0,0);
      o[0][1] = __builtin_amdgcn_mfma_f32_32x32x16_bf16(ef0, vb[s][1], o[0][1], 0,0,0);
      o[1][0] = __builtin_amdgcn_mfma_f32_32x32x16_bf16(ef1, vb[s][0], o[1][0], 0,0,0);
      o[1][1] = __builtin_amdgcn_mfma_f32_32x32x16_bf16(ef1, vb[s][1], o[1][1], 0,0,0);
    }
    __builtin_amdgcn_s_setprio(0);
  };

  const int NT = S_/64;   // 32
  STAGE(0, 0); STAGE(1, 1);
  asm volatile("s_waitcnt vmcnt(4)" ::: "memory");
  __builtin_amdgcn_s_barrier();
  asm volatile("" ::: "memory");
  STAGE(2, 2);

  f32x16 eA0, eA1, eB0, eB1;
  u32 w0[4][2], w1[4][2];
  QK(sm + 0*16384, eA0, eA1);

  #pragma unroll 1
  for (int t=0; t<NT; t+=2){
    const unsigned char* B0 = sm + (t%3)*16384;
    const unsigned char* B1 = sm + ((t+1)%3)*16384;
    // ---- tile t (even): consume eA ----
    PACK(eA0, w0, p4a[0]);
    PACK(eA1, w1, p4a[1]);
    PVF(B0 + 8192, w0, w1);
    if (t+1 < NT-1) { asm volatile("s_waitcnt vmcnt(4)" ::: "memory"); }
    else            { asm volatile("s_waitcnt vmcnt(0)" ::: "memory"); }
    __builtin_amdgcn_s_barrier();
    asm volatile("" ::: "memory");
    QK(B1, eB0, eB1);                       // tile t+1 QK: consumed next half-iter
    if (t+3 < NT) STAGE((t+3)%3, t+3);      // overwrites buf[t%3]: reads done pre-barrier
    // ---- tile t+1 (odd): consume eB ----
    PACK(eB0, w0, p4a[0]);
    PACK(eB1, w1, p4a[1]);
    PVF(B1 + 8192, w0, w1);
    if (t+2 < NT){
      if (t+2 < NT-1) { asm volatile("s_waitcnt vmcnt(4)" ::: "memory"); }
      else            { asm volatile("s_waitcnt vmcnt(0)" ::: "memory"); }
      __builtin_amdgcn_s_barrier();
      asm volatile("" ::: "memory");
      QK(sm + ((t+2)%3)*16384, eA0, eA1);
      if (t+4 < NT) STAGE((t+4)%3, t+4);
    }
  }

  // ---- cross-wave (key-half) reduce via LDS, then L4 scale + store ----
  float p4f[2];
  #pragma unroll
  for (int f=0;f<2;++f) p4f[f] = p4a[f].x + p4a[f].y;

  __syncthreads();
  float* red  = (float*)smc;            // [qi][f][ds][lane][16] = 32KB
  float* redp = (float*)(smc + 32768);  // [qi][f][lane] = 1KB
  if (kj==1){
    #pragma unroll
    for (int f=0;f<2;++f){
      #pragma unroll
      for (int ds=0;ds<2;++ds){
        float* dst = red + ((((qi*2+f)*2+ds)*64 + lane)*16);
        #pragma unroll
        for (int r4=0;r4<4;++r4)
          *(float4*)(dst + r4*4) = make_float4(o[f][ds][r4*4],o[f][ds][r4*4+1],o[f][ds][r4*4+2],o[f][ds][r4*4+3]);
      }
      redp[(qi*2+f)*64 + lane] = p4f[f];
    }
  }
  __syncthreads();
  if (kj==0){
    #pragma unroll
    for (int f=0;f<2;++f){
      #pragma unroll
      for (int ds=0;ds<2;++ds){
        const float* srcp = red + ((((qi*2+f)*2+ds)*64 + lane)*16);
        #pragma unroll
        for (int r4=0;r4<4;++r4){
          float4 t = *(const float4*)(srcp + r4*4);
          o[f][ds][r4*4]+=t.x; o[f][ds][r4*4+1]+=t.y; o[f][ds][r4*4+2]+=t.z; o[f][ds][r4*4+3]+=t.w;
        }
      }
      p4f[f] += redp[(qi*2+f)*64 + lane];
      p4f[f] += __shfl_xor(p4f[f], 32);
    }
    float sc0 = GAMMA * rsqrtf(sqrtf(p4f[0]));
    float sc1 = GAMMA * rsqrtf(sqrtf(p4f[1]));
    #pragma unroll
    for (int f=0;f<2;++f){
      #pragma unroll
      for (int r=0;r<16;++r){
        int qrow = (r&3) + 8*(r>>2) + 4*hi;
        float scr = __shfl(f==0 ? sc0 : sc1, qrow);
        size_t n = (size_t)b*S_ + q0 + f*32 + qrow;
        u16* dst = ao + n*E_ + h*HD_;
        dst[l31]    = f2bf(o[f][0][r] * scr);
        dst[32+l31] = f2bf(o[f][1][r] * scr);
      }
    }
  }
}

// ---------------- K3/K5: 128x128-tile bf16 GEMM (y = A @ Bw^T) with fused epilogues ----------------
template<int MODE>
__global__ __launch_bounds__(256) void k_gemm(
    const u16* __restrict__ A, const u16* __restrict__ Bw,
    const float* __restrict__ bias, const float* __restrict__ aux,
    float* __restrict__ outp)
{
  __shared__ alignas(16) unsigned char sm[32768];
  const int AS=0, BS=16384;
  int tid = threadIdx.x, lane = tid&63, wid = tid>>6;
  int l15 = lane&15, g4 = lane>>4;
  int m0 = blockIdx.y*128, n0 = blockIdx.x*128;
  int wr = wid>>1, wc = wid&1;
  f32x4 z = {0.f,0.f,0.f,0.f};
  f32x4 acc[4][4];
  #pragma unroll
  for (int i=0;i<4;++i)
    #pragma unroll
    for (int j=0;j<4;++j) acc[i][j] = z;

  int srow = tid>>1, scb4 = (tid&1)*4;
  for (int kt=0; kt<E_/64; ++kt){
    int kb = kt*64;
    const uint4* ga = reinterpret_cast<const uint4*>(A  + (size_t)(m0+srow)*E_ + kb);
    const uint4* gb = reinterpret_cast<const uint4*>(Bw + (size_t)(n0+srow)*E_ + kb);
    #pragma unroll
    for (int i=0;i<4;++i){
      uint4 va = ga[scb4+i];
      *(uint4*)(sm + AS + srow*128 + SWZ(srow, (scb4+i)*16)) = va;
    }
    #pragma unroll
    for (int i=0;i<4;++i){
      uint4 vb = gb[scb4+i];
      *(uint4*)(sm + BS + srow*128 + SWZ(srow, (scb4+i)*16)) = vb;
    }
    __syncthreads();
    #pragma unroll
    for (int kk=0;kk<2;++kk){
      int kbyte = kk*64 + g4*16;
      bf16x8 af[4];
      #pragma unroll
      for (int mi=0;mi<4;++mi) af[mi] = ldfrag(sm+AS, wr*64+mi*16+l15, kbyte);
      #pragma unroll
      for (int ni=0;ni<4;++ni){
        bf16x8 bf = ldfrag(sm+BS, wc*64+ni*16+l15, kbyte);
        #pragma unroll
        for (int mi=0;mi<4;++mi)
          acc[mi][ni] = __builtin_amdgcn_mfma_f32_16x16x32_bf16(af[mi], bf, acc[mi][ni], 0,0,0);
      }
    }
    __syncthreads();
  }
  #pragma unroll
  for (int mi=0;mi<4;++mi)
    #pragma unroll
    for (int ni=0;ni<4;++ni)
      #pragma unroll
      for (int r=0;r<4;++r){
        int row = m0 + wr*64 + mi*16 + g4*4 + r;
        int col = n0 + wc*64 + ni*16 + l15;
        size_t idx = (size_t)row*E_ + col;
        float v = acc[mi][ni][r];
        if (MODE == 0){
          outp[idx] = v + bias[col] + aux[idx];
        } else {
          float zz = v + bias[col];
          float gg = 1.f/(1.f + __expf(-zz));
          outp[idx] = aux[idx] * gg;
        }
      }
}

// ---------------- K4: LayerNorm over embed dim; writes fp32 + bf16 copies ----------------
__global__ __launch_bounds__(256) void k_ln(
    const float* __restrict__ xres, const float* __restrict__ lnw, const float* __restrict__ lnb,
    float* __restrict__ x32, u16* __restrict__ x16)
{
  __shared__ float red[8];
  __shared__ float stats[2];
  int row = blockIdx.x, tid = threadIdx.x;
  float4 x = reinterpret_cast<const float4*>(xres + (size_t)row*E_)[tid];
  float s  = x.x + x.y + x.z + x.w;
  float s2 = x.x*x.x + x.y*x.y + x.z*x.z + x.w*x.w;
  #pragma unroll
  for (int m=1;m<64;m<<=1){ s += __shfl_xor(s,m); s2 += __shfl_xor(s2,m); }
  if ((tid&63)==0){ red[tid>>6] = s; red[4+(tid>>6)] = s2; }
  __syncthreads();
  if (tid==0){
    float ts  = red[0]+red[1]+red[2]+red[3];
    float ts2 = red[4]+red[5]+red[6]+red[7];
    float mu  = ts * (1.f/E_);
    float var = ts2 * (1.f/E_) - mu*mu;
    stats[0] = mu; stats[1] = rsqrtf(var + 1e-5f);
  }
  __syncthreads();
  float mu = stats[0], rstd = stats[1];
  float4 w  = reinterpret_cast<const float4*>(lnw)[tid];
  float4 bb = reinterpret_cast<const float4*>(lnb)[tid];
  float4 y;
  y.x = (x.x-mu)*rstd*w.x + bb.x;
  y.y = (x.y-mu)*rstd*w.y + bb.y;
  y.z = (x.z-mu)*rstd*w.z + bb.z;
  y.w = (x.w-mu)*rstd*w.w + bb.w;
  reinterpret_cast<float4*>(x32 + (size_t)row*E_)[tid] = y;
  ushort4 p; p.x = f2bf(y.x); p.y = f2bf(y.y); p.z = f2bf(y.z); p.w = f2bf(y.w);
  reinterpret_cast<ushort4*>(x16 + (size_t)row*E_)[tid] = p;
}

// ---------------- host launch ----------------
extern "C" void kernel_launch(void* const* d_in, const int* in_sizes, int n_in,
                              void* d_out, int out_size, void* d_ws, size_t ws_size,
                              hipStream_t stream)
{
  const float* value = (const float*)d_in[0];
  const float* key   = (const float*)d_in[1];
  const float* query = (const float*)d_in[2];
  const float* Wq    = (const float*)d_in[3];
  const float* Wk    = (const float*)d_in[4];
  const float* Wv    = (const float*)d_in[5];
  const float* Wo    = (const float*)d_in[6];
  const float* bo    = (const float*)d_in[7];
  const float* lnw   = (const float*)d_in[8];
  const float* lnb   = (const float*)d_in[9];
  const float* Wsq   = (const float*)d_in[10];
  const float* bsq   = (const float*)d_in[11];
  float* out = (float*)d_out;

  char* ws = (char*)d_ws;
  const size_t MB = 1ull<<20;
  u16*   qp    = (u16*)  (ws + 0*MB);
  u16*   kp    = (u16*)  (ws + 8*MB);
  u16*   vnT   = (u16*)  (ws + 16*MB);
  u16*   ao    = (u16*)  (ws + 24*MB);
  float* xres  = (float*)(ws + 8*MB);
  u16*   x16   = (u16*)  (ws + 0*MB);
  float* x32   = (float*)(ws + 32*MB);
  u16*   wo16  = (u16*)  (ws + 48*MB);
  u16*   wsq16 = (u16*)  (ws + 50*MB);

  k_cvt <<<2048, 256, 0, stream>>>(Wo, Wsq, wo16, wsq16);
  k_proj<<<dim3(N_/64, H_), 256, 0, stream>>>(query, key, value, Wq, Wk, Wv, qp, kp, vnT);
  k_attn<<<512, 256, 0, stream>>>(qp, kp, vnT, ao);
  k_gemm<0><<<dim3(E_/128, N_/128), 256, 0, stream>>>(ao, wo16, bo, query, xres);
  k_ln  <<<N_, 256, 0, stream>>>(xres, lnw, lnb, x32, x16);
  k_gemm<1><<<dim3(E_/128, N_/128), 256, 0, stream>>>(x16, wsq16, bsq, x32, out);
}

// Round 8
// 109.459 us; speedup vs baseline: 1.8909x; 1.2029x over previous
//
#include <hip/hip_runtime.h>
#include <stdint.h>

#define B_ 2
#define S_ 2048
#define E_ 1024
#define H_ 16
#define HD_ 64
#define N_ (B_*S_)
#define BH_ (B_*H_)
#define GAMMA 0.01f

typedef __attribute__((ext_vector_type(8))) short bf16x8;
typedef __attribute__((ext_vector_type(4))) float f32x4;
typedef __attribute__((ext_vector_type(2))) float f32x2;
typedef __attribute__((ext_vector_type(16))) float f32x16;
typedef __attribute__((ext_vector_type(4))) unsigned int u32x4;
typedef unsigned short u16;
typedef unsigned int u32;

// byte-level XOR swizzle within a 128B row: kills stride-128 bank conflicts,
// preserves 16B-chunk contiguity
#define SWZ(row, kb) ((kb) ^ (((row)&7)<<4))

__device__ __forceinline__ u16 f2bf(float f){
  union { float f; u32 u; } v; v.f = f;
  return (u16)((v.u + 0x7FFFu + ((v.u>>16)&1u)) >> 16);
}

__device__ __forceinline__ float bf2f(u16 u){
  union { u32 u; float f; } v; v.u = ((u32)u)<<16; return v.f;
}

__device__ __forceinline__ u32 cvt_pk_bf16(float lo, float hi){
  u32 r; asm("v_cvt_pk_bf16_f32 %0, %1, %2" : "=v"(r) : "v"(lo), "v"(hi)); return r;
}

__device__ __forceinline__ uint4 pack8(float4 a, float4 b){
  uint4 r;
  r.x = (u32)f2bf(a.x) | ((u32)f2bf(a.y)<<16);
  r.y = (u32)f2bf(a.z) | ((u32)f2bf(a.w)<<16);
  r.z = (u32)f2bf(b.x) | ((u32)f2bf(b.y)<<16);
  r.w = (u32)f2bf(b.z) | ((u32)f2bf(b.w)<<16);
  return r;
}

__device__ __forceinline__ bf16x8 ldfrag(const unsigned char* base, int row, int kbyte){
  return *reinterpret_cast<const bf16x8*>(base + row*128 + SWZ(row, kbyte));
}

// async global->LDS, 16B per lane; LDS dest = wave-uniform base + lane*16 (linear),
// swizzling achieved by permuting the per-lane SOURCE address (m173 pattern)
__device__ __forceinline__ void gl_lds16(const void* g, void* l){
  __builtin_amdgcn_global_load_lds(
      (const __attribute__((address_space(1))) unsigned int*)g,
      (__attribute__((address_space(3))) unsigned int*)l, 16, 0, 0);
}

// ---------------- K0: convert Wo, Wsq fp32 -> bf16 ----------------
__global__ __launch_bounds__(256) void k_cvt(const float* __restrict__ Wo, const float* __restrict__ Wsq,
                                             u16* __restrict__ wo16, u16* __restrict__ wsq16)
{
  int gid = blockIdx.x*256 + threadIdx.x;
  int n4 = (E_*E_)/4;
  const float4* src; ushort4* dst; int i;
  if (gid < n4){ src = (const float4*)Wo;  dst = (ushort4*)wo16;  i = gid; }
  else         { src = (const float4*)Wsq; dst = (ushort4*)wsq16; i = gid - n4; }
  float4 v = src[i];
  ushort4 p; p.x = f2bf(v.x); p.y = f2bf(v.y); p.z = f2bf(v.z); p.w = f2bf(v.w);
  dst[i] = p;
}

// ---------------- K1: per-head QKV projection + xnorm(v), V transposed ----------------
__device__ __forceinline__ void proj_mfma(const unsigned char* X, const unsigned char* W,
                                          int wid, int l15, int g4, f32x4 acc[4])
{
  f32x4 z = {0.f,0.f,0.f,0.f};
  acc[0]=z; acc[1]=z; acc[2]=z; acc[3]=z;
  #pragma unroll
  for (int kk=0;kk<2;++kk){
    int kbyte = kk*64 + g4*16;
    bf16x8 a = ldfrag(X, wid*16 + l15, kbyte);
    #pragma unroll
    for (int t=0;t<4;++t){
      bf16x8 w = ldfrag(W, t*16 + l15, kbyte);
      acc[t] = __builtin_amdgcn_mfma_f32_16x16x32_bf16(a, w, acc[t], 0, 0, 0);
    }
  }
}

__global__ __launch_bounds__(256) void k_proj(
    const float* __restrict__ qin, const float* __restrict__ kin, const float* __restrict__ vin,
    const float* __restrict__ Wq, const float* __restrict__ Wk, const float* __restrict__ Wv,
    u16* __restrict__ qp, u16* __restrict__ kp, u16* __restrict__ vnT)
{
  __shared__ alignas(16) unsigned char sm[57344];
  const int XQ=0, XK=8192, XV=16384, WQS=24576, WKS=32768, WVS=40960, VT=49152;
  int tid = threadIdx.x, lane = tid&63, wid = tid>>6;
  int l15 = lane&15, g4 = lane>>4;
  int tb = blockIdx.x*64;
  int h  = blockIdx.y;
  int b  = tb >> 11;
  int sbase = tb & 2047;
  int bh = b*H_ + h;

  {
    int rl = tid>>2;
    int d0 = (tid&3)*16;
    const float* xs[3] = { qin, kin, vin };
    const float* wsrc[3] = { Wq, Wk, Wv };
    const int xoff[3] = {XQ,XK,XV}, woff[3] = {WQS,WKS,WVS};
    #pragma unroll
    for (int m3=0;m3<3;++m3){
      const float4* gx = reinterpret_cast<const float4*>(xs[m3] + (size_t)(tb+rl)*E_ + h*HD_ + d0);
      float4 a=gx[0], bb=gx[1], c=gx[2], d=gx[3];
      *(uint4*)(sm + xoff[m3] + rl*128 + SWZ(rl, d0*2))    = pack8(a,bb);
      *(uint4*)(sm + xoff[m3] + rl*128 + SWZ(rl, d0*2+16)) = pack8(c,d);
      const float4* gw = reinterpret_cast<const float4*>(wsrc[m3] + rl*64 + d0);
      float4 e=gw[0], f=gw[1], g2=gw[2], h2=gw[3];
      *(uint4*)(sm + woff[m3] + rl*128 + SWZ(rl, d0*2))    = pack8(e,f);
      *(uint4*)(sm + woff[m3] + rl*128 + SWZ(rl, d0*2+16)) = pack8(g2,h2);
    }
  }
  __syncthreads();

  f32x4 acc[4];
  proj_mfma(sm+XQ, sm+WQS, wid, l15, g4, acc);
  #pragma unroll
  for (int t=0;t<4;++t)
    #pragma unroll
    for (int r=0;r<4;++r){
      int tokl = wid*16 + g4*4 + r;
      qp[((size_t)bh*S_ + sbase + tokl)*HD_ + t*16 + l15] = f2bf(acc[t][r]);
    }
  proj_mfma(sm+XK, sm+WKS, wid, l15, g4, acc);
  #pragma unroll
  for (int t=0;t<4;++t)
    #pragma unroll
    for (int r=0;r<4;++r){
      int tokl = wid*16 + g4*4 + r;
      kp[((size_t)bh*S_ + sbase + tokl)*HD_ + t*16 + l15] = f2bf(acc[t][r]);
    }
  proj_mfma(sm+XV, sm+WVS, wid, l15, g4, acc);
  {
    float p4r[4] = {0.f,0.f,0.f,0.f};
    #pragma unroll
    for (int t=0;t<4;++t)
      #pragma unroll
      for (int r=0;r<4;++r){ float e = acc[t][r]; float e2 = e*e; p4r[r] += e2*e2; }
    #pragma unroll
    for (int r=0;r<4;++r){
      float p = p4r[r];
      p += __shfl_xor(p,1); p += __shfl_xor(p,2); p += __shfl_xor(p,4); p += __shfl_xor(p,8);
      p4r[r] = GAMMA / sqrtf(sqrtf(p));
    }
    #pragma unroll
    for (int t=0;t<4;++t)
      #pragma unroll
      for (int r=0;r<4;++r){
        int tokl = wid*16 + g4*4 + r;
        int dd = t*16 + l15;
        *(u16*)(sm + VT + dd*128 + SWZ(dd, tokl*2)) = f2bf(acc[t][r] * p4r[r]);
      }
  }
  __syncthreads();
  {
    int dd = tid>>2; int c2 = tid&3;
    size_t gbase = ((size_t)bh*HD_ + dd)*S_ + sbase + c2*16;
    uint4 v0 = *(const uint4*)(sm + VT + dd*128 + SWZ(dd, c2*32));
    uint4 v1 = *(const uint4*)(sm + VT + dd*128 + SWZ(dd, c2*32+16));
    *(uint4*)(vnT + gbase)     = v0;
    *(uint4*)(vnT + gbase + 8) = v1;
  }
}

// ---------------- K2: flash attention (unchanged from round 6) ----------------
__global__ __launch_bounds__(256, 2) void k_attn(
    const u16* __restrict__ qp, const u16* __restrict__ kp,
    const u16* __restrict__ vnT, u16* __restrict__ ao)
{
  __shared__ alignas(128) unsigned char sm[49152];   // 3 x (K 8KB + V 8KB)
  char* smc = (char*)sm;
  int tid = threadIdx.x, lane = tid&63, wv = tid>>6;
  int l31 = lane&31, hi = lane>>5;
  int qi = wv>>1, kj = wv&1;
  int L = blockIdx.x;
  int xcd = L&7, iw = L>>3;            // iw 0..63
  int bh = xcd*4 + (iw&3);
  int qx = iw>>2;                      // 0..15
  int qb = qx*128;
  int b = bh>>4, h = bh&15;
  const u16* Kb = kp  + (size_t)bh*S_*HD_;
  const u16* Vb = vnT + (size_t)bh*HD_*S_;
  const u16* Qb = qp  + (size_t)bh*S_*HD_;
  int q0 = qb + qi*64;

  bf16x8 qf[2][4];
  #pragma unroll
  for (int f=0;f<2;++f)
    #pragma unroll
    for (int kk=0;kk<4;++kk)
      qf[f][kk] = *reinterpret_cast<const bf16x8*>(Qb + (size_t)(q0 + f*32 + l31)*HD_ + kk*16 + hi*8);

  f32x16 z16 = {};
  f32x16 o[2][2];
  #pragma unroll
  for (int f=0;f<2;++f){ o[f][0] = z16; o[f][1] = z16; }
  f32x2 p4a[2] = {{0.f,0.f},{0.f,0.f}};

  int off0 = wv*2048 + lane*16;
  int row0 = off0 >> 7, col0 = (off0 & 127) ^ ((row0 & 7) << 4);
  int off1 = off0 + 1024;
  int row1 = off1 >> 7, col1 = (off1 & 127) ^ ((row1 & 7) << 4);
  const char* kSrc0 = (const char*)Kb + row0*128 + col0;
  const char* kSrc1 = (const char*)Kb + row1*128 + col1;
  const char* vSrc0 = (const char*)Vb + (size_t)row0*4096 + col0;
  const char* vSrc1 = (const char*)Vb + (size_t)row1*4096 + col1;
  unsigned dOfs = wv*2048;

  auto STAGE = [&](int bsel, int kt){
    char* db = smc + bsel*16384 + dOfs;
    gl_lds16(kSrc0 + (size_t)kt*8192, db);
    gl_lds16(kSrc1 + (size_t)kt*8192, db + 1024);
    gl_lds16(vSrc0 + (size_t)kt*128,  db + 8192);
    gl_lds16(vSrc1 + (size_t)kt*128,  db + 8192 + 1024);
  };

  auto PACK = [&](const f32x16& e, u32 (&w)[4][2], f32x2& pa){
    #pragma unroll
    for (int j=0;j<8;++j){
      const int g=j>>1, i=j&1;
      float a = e[4*g+2*i], c = e[4*g+2*i+1];
      f32x2 pr = {a, c};
      f32x2 e2;
      asm("v_pk_mul_f32 %0, %1, %1" : "=v"(e2) : "v"(pr));
      asm("v_pk_fma_f32 %0, %1, %1, %0" : "+v"(pa) : "v"(e2));
      w[g][i] = cvt_pk_bf16(a, c);
    }
  };
  auto AFRAG = [&](u32 (&w)[4][2], int s) -> bf16x8 {
    u32 a0 = w[2*s][0], b0 = w[2*s+1][0];
    u32 a1 = w[2*s][1], b1 = w[2*s+1][1];
    asm("v_permlane32_swap_b32 %0, %1" : "+v"(a0), "+v"(b0));
    asm("v_permlane32_swap_b32 %0, %1" : "+v"(a1), "+v"(b1));
    u32x4 fw = {a0, a1, b0, b1};
    return __builtin_bit_cast(bf16x8, fw);
  };

  auto QK = [&](const unsigned char* K_, f32x16& E0, f32x16& E1){
    bf16x8 ka[4];
    #pragma unroll
    for (int kk=0;kk<4;++kk) ka[kk] = ldfrag(K_, kj*32 + l31, kk*32 + hi*16);
    E0 = z16; E1 = z16;
    __builtin_amdgcn_s_setprio(1);
    #pragma unroll
    for (int kk=0;kk<4;++kk){
      E0 = __builtin_amdgcn_mfma_f32_32x32x16_bf16(ka[kk], qf[0][kk], E0, 0,0,0);
      E1 = __builtin_amdgcn_mfma_f32_32x32x16_bf16(ka[kk], qf[1][kk], E1, 0,0,0);
    }
    __builtin_amdgcn_s_setprio(0);
  };

  auto PVF = [&](const unsigned char* V_, u32 (&w0)[4][2], u32 (&w1)[4][2]){
    bf16x8 vb[2][2];
    #pragma unroll
    for (int s=0;s<2;++s){
      vb[s][0] = ldfrag(V_, l31,    kj*64 + s*32 + hi*16);
      vb[s][1] = ldfrag(V_, 32+l31, kj*64 + s*32 + hi*16);
    }
    __builtin_amdgcn_s_setprio(1);
    #pragma unroll
    for (int s=0;s<2;++s){
      bf16x8 ef0 = AFRAG(w0, s);
      bf16x8 ef1 = AFRAG(w1, s);
      o[0][0] = __builtin_amdgcn_mfma_f32_32x32x16_bf16(ef0, vb[s][0], o[0][0], 0,0,0);
      o[0][1] = __builtin_amdgcn_mfma_f32_32x32x16_bf16(ef0, vb[s][1], o[0][1], 0,0,0);
      o[1][0] = __builtin_amdgcn_mfma_f32_32x32x16_bf16(ef1, vb[s][0], o[1][0], 0,0,0);
      o[1][1] = __builtin_amdgcn_mfma_f32_32x32x16_bf16(ef1, vb[s][1], o[1][1], 0,0,0);
    }
    __builtin_amdgcn_s_setprio(0);
  };

  const int NT = S_/64;   // 32
  STAGE(0, 0); STAGE(1, 1);
  asm volatile("s_waitcnt vmcnt(4)" ::: "memory");
  __builtin_amdgcn_s_barrier();
  asm volatile("" ::: "memory");
  STAGE(2, 2);

  f32x16 eA0, eA1, eB0, eB1;
  u32 w0[4][2], w1[4][2];
  QK(sm + 0*16384, eA0, eA1);

  #pragma unroll 1
  for (int t=0; t<NT; t+=2){
    const unsigned char* B0 = sm + (t%3)*16384;
    const unsigned char* B1 = sm + ((t+1)%3)*16384;
    PACK(eA0, w0, p4a[0]);
    PACK(eA1, w1, p4a[1]);
    PVF(B0 + 8192, w0, w1);
    if (t+1 < NT-1) { asm volatile("s_waitcnt vmcnt(4)" ::: "memory"); }
    else            { asm volatile("s_waitcnt vmcnt(0)" ::: "memory"); }
    __builtin_amdgcn_s_barrier();
    asm volatile("" ::: "memory");
    QK(B1, eB0, eB1);
    if (t+3 < NT) STAGE((t+3)%3, t+3);
    PACK(eB0, w0, p4a[0]);
    PACK(eB1, w1, p4a[1]);
    PVF(B1 + 8192, w0, w1);
    if (t+2 < NT){
      if (t+2 < NT-1) { asm volatile("s_waitcnt vmcnt(4)" ::: "memory"); }
      else            { asm volatile("s_waitcnt vmcnt(0)" ::: "memory"); }
      __builtin_amdgcn_s_barrier();
      asm volatile("" ::: "memory");
      QK(sm + ((t+2)%3)*16384, eA0, eA1);
      if (t+4 < NT) STAGE((t+4)%3, t+4);
    }
  }

  float p4f[2];
  #pragma unroll
  for (int f=0;f<2;++f) p4f[f] = p4a[f].x + p4a[f].y;

  __syncthreads();
  float* red  = (float*)smc;
  float* redp = (float*)(smc + 32768);
  if (kj==1){
    #pragma unroll
    for (int f=0;f<2;++f){
      #pragma unroll
      for (int ds=0;ds<2;++ds){
        float* dst = red + ((((qi*2+f)*2+ds)*64 + lane)*16);
        #pragma unroll
        for (int r4=0;r4<4;++r4)
          *(float4*)(dst + r4*4) = make_float4(o[f][ds][r4*4],o[f][ds][r4*4+1],o[f][ds][r4*4+2],o[f][ds][r4*4+3]);
      }
      redp[(qi*2+f)*64 + lane] = p4f[f];
    }
  }
  __syncthreads();
  if (kj==0){
    #pragma unroll
    for (int f=0;f<2;++f){
      #pragma unroll
      for (int ds=0;ds<2;++ds){
        const float* srcp = red + ((((qi*2+f)*2+ds)*64 + lane)*16);
        #pragma unroll
        for (int r4=0;r4<4;++r4){
          float4 t = *(const float4*)(srcp + r4*4);
          o[f][ds][r4*4]+=t.x; o[f][ds][r4*4+1]+=t.y; o[f][ds][r4*4+2]+=t.z; o[f][ds][r4*4+3]+=t.w;
        }
      }
      p4f[f] += redp[(qi*2+f)*64 + lane];
      p4f[f] += __shfl_xor(p4f[f], 32);
    }
    float sc0 = GAMMA * rsqrtf(sqrtf(p4f[0]));
    float sc1 = GAMMA * rsqrtf(sqrtf(p4f[1]));
    #pragma unroll
    for (int f=0;f<2;++f){
      #pragma unroll
      for (int r=0;r<16;++r){
        int qrow = (r&3) + 8*(r>>2) + 4*hi;
        float scr = __shfl(f==0 ? sc0 : sc1, qrow);
        size_t n = (size_t)b*S_ + q0 + f*32 + qrow;
        u16* dst = ao + n*E_ + h*HD_;
        dst[l31]    = f2bf(o[f][0][r] * scr);
        dst[32+l31] = f2bf(o[f][1][r] * scr);
      }
    }
  }
}

// ---------------- K3/K5: 128x64-tile bf16 GEMM (y = A @ Bw^T), T3/T4 pipeline ----------------
// BM=128, BN=64, BK=64; grid 512 (2 blocks/CU); 4 waves = 2wr x 2wc, wave = 64x32
// via 32x32x16 MFMA (B-frag reused across 2 row-groups). gl_lds staging with
// pre-swizzled source, 3 x 24KB buffers, ONE s_barrier + counted vmcnt(6)/K-step.
// MODE 0: out16[idx] = bf16(acc + bias[col] + auxf[idx])            (Wo proj + residual)
// MODE 1: out32[idx] = bf2f(aux16[idx]) * sigmoid(acc + bias[col])  (SE gate)
template<int MODE>
__global__ __launch_bounds__(256, 2) void k_gemm(
    const u16* __restrict__ A, const u16* __restrict__ Bw,
    const float* __restrict__ bias, const float* __restrict__ auxf,
    const u16* __restrict__ aux16, float* __restrict__ out32, u16* __restrict__ out16)
{
  __shared__ alignas(128) unsigned char sm[73728];   // 3 x (A 16KB + B 8KB)
  char* smc = (char*)sm;
  int tid = threadIdx.x, lane = tid&63, wv = tid>>6;
  int l31 = lane&31, hi = lane>>5;
  int wr = wv>>1, wc = wv&1;
  // XCD swizzle: each XCD gets 4 contiguous m-panels (A panel L2-resident)
  int LL = (blockIdx.x & 7)*64 + (blockIdx.x >> 3);   // 512 = 8 XCD x 64
  int mt = LL >> 4, nt = LL & 15;                     // 32 m-tiles x 16 n-tiles
  int m0 = mt*128, n0 = nt*64;

  // staging source addresses (pre-swizzled col within 128B row)
  int ric  = lane>>3;                                 // row in 8-row chunk
  int colb = ((lane&7)*16) ^ ((ric&7)<<4);
  const char* aSrc[4]; const char* bSrc[2];
  #pragma unroll
  for (int j=0;j<4;++j)
    aSrc[j] = (const char*)A  + ((size_t)(m0 + wv*32 + 8*j + ric)*E_)*2 + colb;
  #pragma unroll
  for (int j=0;j<2;++j)
    bSrc[j] = (const char*)Bw + ((size_t)(n0 + wv*16 + 8*j + ric)*E_)*2 + colb;

  auto STAGE = [&](int bsel, int t){
    char* db = smc + bsel*24576;
    size_t kb2 = (size_t)t*128;                        // 64 k * 2B
    #pragma unroll
    for (int j=0;j<4;++j) gl_lds16(aSrc[j] + kb2, db + (wv*4+j)*1024);
    #pragma unroll
    for (int j=0;j<2;++j) gl_lds16(bSrc[j] + kb2, db + 16384 + (wv*2+j)*1024);
  };

  f32x16 acc[2] = {{}, {}};

  const int NK = E_/64;   // 16
  STAGE(0, 0); STAGE(1, 1);

  #pragma unroll 1
  for (int t=0; t<NK; ++t){
    if (t < NK-1) { asm volatile("s_waitcnt vmcnt(6)" ::: "memory"); }
    else          { asm volatile("s_waitcnt vmcnt(0)" ::: "memory"); }
    __builtin_amdgcn_s_barrier();
    asm volatile("" ::: "memory");
    if (t+2 < NK) STAGE((t+2)%3, t+2);

    const unsigned char* Ap_ = sm + (t%3)*24576;
    const unsigned char* Bp_ = Ap_ + 16384;
    #pragma unroll
    for (int kk=0;kk<4;++kk){
      bf16x8 bfr = ldfrag(Bp_, wc*32 + l31, kk*32 + hi*16);
      bf16x8 af0 = ldfrag(Ap_, wr*64 + l31,      kk*32 + hi*16);
      bf16x8 af1 = ldfrag(Ap_, wr*64 + 32 + l31, kk*32 + hi*16);
      __builtin_amdgcn_s_setprio(1);
      acc[0] = __builtin_amdgcn_mfma_f32_32x32x16_bf16(af0, bfr, acc[0], 0,0,0);
      acc[1] = __builtin_amdgcn_mfma_f32_32x32x16_bf16(af1, bfr, acc[1], 0,0,0);
      __builtin_amdgcn_s_setprio(0);
    }
  }

  // epilogue: lane holds D[col = n0+wc*32+l31][m = m0+wr*64+rg*32+crow(r,hi)]
  int col = n0 + wc*32 + l31;
  float bi = bias[col];
  #pragma unroll
  for (int rg=0;rg<2;++rg)
    #pragma unroll
    for (int r=0;r<16;++r){
      int mrow = m0 + wr*64 + rg*32 + (r&3) + 8*(r>>2) + 4*hi;
      size_t idx = (size_t)mrow*E_ + col;
      float v = acc[rg][r] + bi;
      if (MODE == 0){
        out16[idx] = f2bf(v + auxf[idx]);
      } else {
        float gg = 1.f/(1.f + __expf(-v));
        out32[idx] = bf2f(aux16[idx]) * gg;
      }
    }
}

// ---------------- K4: LayerNorm over embed dim; bf16 in -> bf16 out ----------------
__global__ __launch_bounds__(256) void k_ln(
    const u16* __restrict__ xin, const float* __restrict__ lnw, const float* __restrict__ lnb,
    u16* __restrict__ xout)
{
  __shared__ float red[8];
  __shared__ float stats[2];
  int row = blockIdx.x, tid = threadIdx.x;
  ushort4 xr = reinterpret_cast<const ushort4*>(xin + (size_t)row*E_)[tid];
  float x0 = bf2f(xr.x), x1 = bf2f(xr.y), x2 = bf2f(xr.z), x3 = bf2f(xr.w);
  float s  = x0 + x1 + x2 + x3;
  float s2 = x0*x0 + x1*x1 + x2*x2 + x3*x3;
  #pragma unroll
  for (int m=1;m<64;m<<=1){ s += __shfl_xor(s,m); s2 += __shfl_xor(s2,m); }
  if ((tid&63)==0){ red[tid>>6] = s; red[4+(tid>>6)] = s2; }
  __syncthreads();
  if (tid==0){
    float ts  = red[0]+red[1]+red[2]+red[3];
    float ts2 = red[4]+red[5]+red[6]+red[7];
    float mu  = ts * (1.f/E_);
    float var = ts2 * (1.f/E_) - mu*mu;
    stats[0] = mu; stats[1] = rsqrtf(var + 1e-5f);
  }
  __syncthreads();
  float mu = stats[0], rstd = stats[1];
  float4 w  = reinterpret_cast<const float4*>(lnw)[tid];
  float4 bb = reinterpret_cast<const float4*>(lnb)[tid];
  ushort4 p;
  p.x = f2bf((x0-mu)*rstd*w.x + bb.x);
  p.y = f2bf((x1-mu)*rstd*w.y + bb.y);
  p.z = f2bf((x2-mu)*rstd*w.z + bb.z);
  p.w = f2bf((x3-mu)*rstd*w.w + bb.w);
  reinterpret_cast<ushort4*>(xout + (size_t)row*E_)[tid] = p;
}

// ---------------- host launch ----------------
extern "C" void kernel_launch(void* const* d_in, const int* in_sizes, int n_in,
                              void* d_out, int out_size, void* d_ws, size_t ws_size,
                              hipStream_t stream)
{
  const float* value = (const float*)d_in[0];
  const float* key   = (const float*)d_in[1];
  const float* query = (const float*)d_in[2];
  const float* Wq    = (const float*)d_in[3];
  const float* Wk    = (const float*)d_in[4];
  const float* Wv    = (const float*)d_in[5];
  const float* Wo    = (const float*)d_in[6];
  const float* bo    = (const float*)d_in[7];
  const float* lnw   = (const float*)d_in[8];
  const float* lnb   = (const float*)d_in[9];
  const float* Wsq   = (const float*)d_in[10];
  const float* bsq   = (const float*)d_in[11];
  float* out = (float*)d_out;

  char* ws = (char*)d_ws;
  const size_t MB = 1ull<<20;
  u16*   qp     = (u16*)(ws + 0*MB);    // K1->K2
  u16*   kp     = (u16*)(ws + 8*MB);    // K1->K2
  u16*   vnT    = (u16*)(ws + 16*MB);   // K1->K2
  u16*   ao     = (u16*)(ws + 24*MB);   // K2->K3 (8MB)
  u16*   xres16 = (u16*)(ws + 8*MB);    // K3->K4 (8MB, over kp)
  u16*   x16    = (u16*)(ws + 16*MB);   // K4->K5 (8MB, over vnT)
  u16*   wo16   = (u16*)(ws + 48*MB);
  u16*   wsq16  = (u16*)(ws + 50*MB);

  k_cvt <<<2048, 256, 0, stream>>>(Wo, Wsq, wo16, wsq16);
  k_proj<<<dim3(N_/64, H_), 256, 0, stream>>>(query, key, value, Wq, Wk, Wv, qp, kp, vnT);
  k_attn<<<512, 256, 0, stream>>>(qp, kp, vnT, ao);
  k_gemm<0><<<512, 256, 0, stream>>>(ao, wo16, bo, query, (const u16*)nullptr, (float*)nullptr, xres16);
  k_ln  <<<N_, 256, 0, stream>>>(xres16, lnw, lnb, x16);
  k_gemm<1><<<512, 256, 0, stream>>>(x16, wsq16, bsq, (const float*)nullptr, x16, out, (u16*)nullptr);
}

// Round 9
// 108.606 us; speedup vs baseline: 1.9058x; 1.0079x over previous
//
#include <hip/hip_runtime.h>
#include <stdint.h>

#define B_ 2
#define S_ 2048
#define E_ 1024
#define H_ 16
#define HD_ 64
#define N_ (B_*S_)
#define BH_ (B_*H_)
#define GAMMA 0.01f

typedef __attribute__((ext_vector_type(8))) short bf16x8;
typedef __attribute__((ext_vector_type(4))) float f32x4;
typedef __attribute__((ext_vector_type(2))) float f32x2;
typedef __attribute__((ext_vector_type(16))) float f32x16;
typedef __attribute__((ext_vector_type(4))) unsigned int u32x4;
typedef unsigned short u16;
typedef unsigned int u32;

// byte-level XOR swizzle within a 128B row
#define SWZ(row, kb) ((kb) ^ (((row)&7)<<4))

__device__ __forceinline__ u16 f2bf(float f){
  union { float f; u32 u; } v; v.f = f;
  return (u16)((v.u + 0x7FFFu + ((v.u>>16)&1u)) >> 16);
}

__device__ __forceinline__ float bf2f(u16 u){
  union { u32 u; float f; } v; v.u = ((u32)u)<<16; return v.f;
}

__device__ __forceinline__ u32 cvt_pk_bf16(float lo, float hi){
  u32 r; asm("v_cvt_pk_bf16_f32 %0, %1, %2" : "=v"(r) : "v"(lo), "v"(hi)); return r;
}

__device__ __forceinline__ uint4 pack8(float4 a, float4 b){
  uint4 r;
  r.x = (u32)f2bf(a.x) | ((u32)f2bf(a.y)<<16);
  r.y = (u32)f2bf(a.z) | ((u32)f2bf(a.w)<<16);
  r.z = (u32)f2bf(b.x) | ((u32)f2bf(b.y)<<16);
  r.w = (u32)f2bf(b.z) | ((u32)f2bf(b.w)<<16);
  return r;
}

__device__ __forceinline__ bf16x8 ldfrag(const unsigned char* base, int row, int kbyte){
  return *reinterpret_cast<const bf16x8*>(base + row*128 + SWZ(row, kbyte));
}
// V tile has 256B rows; 16-slot swizzle
__device__ __forceinline__ bf16x8 ldfragV(const unsigned char* base, int row, int col){
  return *reinterpret_cast<const bf16x8*>(base + row*256 + (col ^ ((row&15)<<4)));
}

// async global->LDS, 16B/lane; LDS dest = wave-uniform base + lane*16 (linear),
// swizzling achieved by permuting the per-lane SOURCE address
__device__ __forceinline__ void gl_lds16(const void* g, void* l){
  __builtin_amdgcn_global_load_lds(
      (const __attribute__((address_space(1))) unsigned int*)g,
      (__attribute__((address_space(3))) unsigned int*)l, 16, 0, 0);
}

// ---------------- K1: per-head QKV projection + xnorm(v), V transposed ----------------
// blockIdx.y >= H_: weight-conversion slabs (folded former k_cvt)
__device__ __forceinline__ void proj_mfma(const unsigned char* X, const unsigned char* W,
                                          int wid, int l15, int g4, f32x4 acc[4])
{
  f32x4 z = {0.f,0.f,0.f,0.f};
  acc[0]=z; acc[1]=z; acc[2]=z; acc[3]=z;
  #pragma unroll
  for (int kk=0;kk<2;++kk){
    int kbyte = kk*64 + g4*16;
    bf16x8 a = ldfrag(X, wid*16 + l15, kbyte);
    #pragma unroll
    for (int t=0;t<4;++t){
      bf16x8 w = ldfrag(W, t*16 + l15, kbyte);
      acc[t] = __builtin_amdgcn_mfma_f32_16x16x32_bf16(a, w, acc[t], 0, 0, 0);
    }
  }
}

__global__ __launch_bounds__(256) void k_proj(
    const float* __restrict__ qin, const float* __restrict__ kin, const float* __restrict__ vin,
    const float* __restrict__ Wq, const float* __restrict__ Wk, const float* __restrict__ Wv,
    u16* __restrict__ qp, u16* __restrict__ kp, u16* __restrict__ vnT,
    const float* __restrict__ Wo, const float* __restrict__ Wsq,
    u16* __restrict__ wo16, u16* __restrict__ wsq16)
{
  __shared__ alignas(16) unsigned char sm[57344];
  if (blockIdx.y >= H_){
    // weight conversion: 128 blocks grid-stride over 2*(E*E)/4 float4s
    int cblk = (blockIdx.y - H_)*64 + blockIdx.x;
    int n4 = (E_*E_)/4;
    for (int i = cblk*256 + threadIdx.x; i < 2*n4; i += 128*256){
      const float4* src; ushort4* dst; int j;
      if (i < n4){ src=(const float4*)Wo;  dst=(ushort4*)wo16;  j=i; }
      else       { src=(const float4*)Wsq; dst=(ushort4*)wsq16; j=i-n4; }
      float4 v = src[j];
      ushort4 p; p.x=f2bf(v.x); p.y=f2bf(v.y); p.z=f2bf(v.z); p.w=f2bf(v.w);
      dst[j] = p;
    }
    return;
  }
  const int XQ=0, XK=8192, XV=16384, WQS=24576, WKS=32768, WVS=40960, VT=49152;
  int tid = threadIdx.x, lane = tid&63, wid = tid>>6;
  int l15 = lane&15, g4 = lane>>4;
  int tb = blockIdx.x*64;
  int h  = blockIdx.y;
  int b  = tb >> 11;
  int sbase = tb & 2047;
  int bh = b*H_ + h;

  {
    int rl = tid>>2;
    int d0 = (tid&3)*16;
    const float* xs[3] = { qin, kin, vin };
    const float* wsrc[3] = { Wq, Wk, Wv };
    const int xoff[3] = {XQ,XK,XV}, woff[3] = {WQS,WKS,WVS};
    #pragma unroll
    for (int m3=0;m3<3;++m3){
      const float4* gx = reinterpret_cast<const float4*>(xs[m3] + (size_t)(tb+rl)*E_ + h*HD_ + d0);
      float4 a=gx[0], bb=gx[1], c=gx[2], d=gx[3];
      *(uint4*)(sm + xoff[m3] + rl*128 + SWZ(rl, d0*2))    = pack8(a,bb);
      *(uint4*)(sm + xoff[m3] + rl*128 + SWZ(rl, d0*2+16)) = pack8(c,d);
      const float4* gw = reinterpret_cast<const float4*>(wsrc[m3] + rl*64 + d0);
      float4 e=gw[0], f=gw[1], g2=gw[2], h2=gw[3];
      *(uint4*)(sm + woff[m3] + rl*128 + SWZ(rl, d0*2))    = pack8(e,f);
      *(uint4*)(sm + woff[m3] + rl*128 + SWZ(rl, d0*2+16)) = pack8(g2,h2);
    }
  }
  __syncthreads();

  f32x4 acc[4];
  proj_mfma(sm+XQ, sm+WQS, wid, l15, g4, acc);
  #pragma unroll
  for (int t=0;t<4;++t)
    #pragma unroll
    for (int r=0;r<4;++r){
      int tokl = wid*16 + g4*4 + r;
      qp[((size_t)bh*S_ + sbase + tokl)*HD_ + t*16 + l15] = f2bf(acc[t][r]);
    }
  proj_mfma(sm+XK, sm+WKS, wid, l15, g4, acc);
  #pragma unroll
  for (int t=0;t<4;++t)
    #pragma unroll
    for (int r=0;r<4;++r){
      int tokl = wid*16 + g4*4 + r;
      kp[((size_t)bh*S_ + sbase + tokl)*HD_ + t*16 + l15] = f2bf(acc[t][r]);
    }
  proj_mfma(sm+XV, sm+WVS, wid, l15, g4, acc);
  {
    float p4r[4] = {0.f,0.f,0.f,0.f};
    #pragma unroll
    for (int t=0;t<4;++t)
      #pragma unroll
      for (int r=0;r<4;++r){ float e = acc[t][r]; float e2 = e*e; p4r[r] += e2*e2; }
    #pragma unroll
    for (int r=0;r<4;++r){
      float p = p4r[r];
      p += __shfl_xor(p,1); p += __shfl_xor(p,2); p += __shfl_xor(p,4); p += __shfl_xor(p,8);
      p4r[r] = GAMMA / sqrtf(sqrtf(p));
    }
    #pragma unroll
    for (int t=0;t<4;++t)
      #pragma unroll
      for (int r=0;r<4;++r){
        int tokl = wid*16 + g4*4 + r;
        int dd = t*16 + l15;
        *(u16*)(sm + VT + dd*128 + SWZ(dd, tokl*2)) = f2bf(acc[t][r] * p4r[r]);
      }
  }
  __syncthreads();
  {
    int dd = tid>>2; int c2 = tid&3;
    size_t gbase = ((size_t)bh*HD_ + dd)*S_ + sbase + c2*16;
    uint4 v0 = *(const uint4*)(sm + VT + dd*128 + SWZ(dd, c2*32));
    uint4 v1 = *(const uint4*)(sm + VT + dd*128 + SWZ(dd, c2*32+16));
    *(uint4*)(vnT + gbase)     = v0;
    *(uint4*)(vnT + gbase + 8) = v1;
  }
}

// ---------------- K2: flash attention, KVBLK=128, Fq=2, permlane exchange ----------------
// Block: 128 q x 128-key tiles, 4 waves = 2qi x 2kj. Wave covers 64q (Fq=2) x 64 keys
// (two 32-key sub-steps s2). 2 x 32KB LDS buffers, 2 barriers per 128-key tile
// (same barrier count as KVBLK=64 but 2x work per interval), vmcnt(8) counted.
// Block ordering: co-resident blocks share bh -> K/V stream L1/L2-shared.
__global__ __launch_bounds__(256, 2) void k_attn(
    const u16* __restrict__ qp, const u16* __restrict__ kp,
    const u16* __restrict__ vnT, u16* __restrict__ ao)
{
  __shared__ alignas(128) unsigned char sm[65536];   // 2 x (K 16KB + V 16KB)
  char* smc = (char*)sm;
  int tid = threadIdx.x, lane = tid&63, wv = tid>>6;
  int l31 = lane&31, hi = lane>>5;
  int qi = wv>>1, kj = wv&1;
  int L = blockIdx.x;
  int xcd = L&7, iw = L>>3;            // iw 0..63
  int bh = xcd*4 + (iw>>4);            // consecutive iw share bh (L1/L2 reuse)
  int qx = iw&15;                      // 0..15
  int qb = qx*128;
  int b = bh>>4, h = bh&15;
  const u16* Kb = kp  + (size_t)bh*S_*HD_;
  const u16* Vb = vnT + (size_t)bh*HD_*S_;
  const u16* Qb = qp  + (size_t)bh*S_*HD_;
  int q0 = qb + qi*64;

  // Q fragments (B-operand): 2 q-frags of 32 rows each
  bf16x8 qf[2][4];
  #pragma unroll
  for (int f=0;f<2;++f)
    #pragma unroll
    for (int kk=0;kk<4;++kk)
      qf[f][kk] = *reinterpret_cast<const bf16x8*>(Qb + (size_t)(q0 + f*32 + l31)*HD_ + kk*16 + hi*8);

  f32x16 z16 = {};
  f32x16 o[2][2];
  #pragma unroll
  for (int f=0;f<2;++f){ o[f][0] = z16; o[f][1] = z16; }
  f32x2 p4a[2] = {{0.f,0.f},{0.f,0.f}};
  f32x2 p4b[2] = {{0.f,0.f},{0.f,0.f}};

  // staging sources (pre-swizzled cols). K tile [128][128B]; V tile [64][256B].
  const char* kSrcC[4]; const char* vSrcC[4];
  #pragma unroll
  for (int c=0;c<4;++c){
    int rk = wv*32 + c*8 + (lane>>3);
    int ck = ((lane&7)*16) ^ ((rk&7)<<4);
    kSrcC[c] = (const char*)Kb + (size_t)rk*128 + ck;
    int rv = wv*16 + c*4 + (lane>>4);
    int cv = ((lane&15)*16) ^ ((rv&15)<<4);
    vSrcC[c] = (const char*)Vb + (size_t)rv*4096 + cv;
  }

  auto STAGE = [&](int bsel, int kt){
    char* db = smc + bsel*32768 + wv*4096;
    #pragma unroll
    for (int c=0;c<4;++c) gl_lds16(kSrcC[c] + (size_t)kt*16384, db + c*1024);
    #pragma unroll
    for (int c=0;c<4;++c) gl_lds16(vSrcC[c] + (size_t)kt*256,   db + 16384 + c*1024);
  };

  auto PACK = [&](const f32x16& e, u32 (&w)[4][2], f32x2& pa){
    #pragma unroll
    for (int j=0;j<8;++j){
      const int g=j>>1, i=j&1;
      float a = e[4*g+2*i], c = e[4*g+2*i+1];
      f32x2 pr = {a, c};
      f32x2 e2;
      asm("v_pk_mul_f32 %0, %1, %1" : "=v"(e2) : "v"(pr));
      asm("v_pk_fma_f32 %0, %1, %1, %0" : "+v"(pa) : "v"(e2));
      w[g][i] = cvt_pk_bf16(a, c);
    }
  };
  auto AFRAG = [&](u32 (&w)[4][2], int s) -> bf16x8 {
    u32 a0 = w[2*s][0], b0 = w[2*s+1][0];
    u32 a1 = w[2*s][1], b1 = w[2*s+1][1];
    asm("v_permlane32_swap_b32 %0, %1" : "+v"(a0), "+v"(b0));
    asm("v_permlane32_swap_b32 %0, %1" : "+v"(a1), "+v"(b1));
    u32x4 fw = {a0, a1, b0, b1};
    return __builtin_bit_cast(bf16x8, fw);
  };

  auto QK = [&](const unsigned char* K_, int s2, f32x16& E0, f32x16& E1){
    bf16x8 ka[4];
    #pragma unroll
    for (int kk=0;kk<4;++kk) ka[kk] = ldfrag(K_, kj*64 + s2*32 + l31, kk*32 + hi*16);
    E0 = z16; E1 = z16;
    __builtin_amdgcn_s_setprio(1);
    #pragma unroll
    for (int kk=0;kk<4;++kk){
      E0 = __builtin_amdgcn_mfma_f32_32x32x16_bf16(ka[kk], qf[0][kk], E0, 0,0,0);
      E1 = __builtin_amdgcn_mfma_f32_32x32x16_bf16(ka[kk], qf[1][kk], E1, 0,0,0);
    }
    __builtin_amdgcn_s_setprio(0);
  };

  auto PVF = [&](const unsigned char* V_, int s2, u32 (&w0)[4][2], u32 (&w1)[4][2]){
    bf16x8 vb[2][2];
    #pragma unroll
    for (int s=0;s<2;++s){
      vb[s][0] = ldfragV(V_, l31,    kj*128 + s2*64 + s*32 + hi*16);
      vb[s][1] = ldfragV(V_, 32+l31, kj*128 + s2*64 + s*32 + hi*16);
    }
    __builtin_amdgcn_s_setprio(1);
    #pragma unroll
    for (int s=0;s<2;++s){
      bf16x8 ef0 = AFRAG(w0, s);
      bf16x8 ef1 = AFRAG(w1, s);
      o[0][0] = __builtin_amdgcn_mfma_f32_32x32x16_bf16(ef0, vb[s][0], o[0][0], 0,0,0);
      o[0][1] = __builtin_amdgcn_mfma_f32_32x32x16_bf16(ef0, vb[s][1], o[0][1], 0,0,0);
      o[1][0] = __builtin_amdgcn_mfma_f32_32x32x16_bf16(ef1, vb[s][0], o[1][0], 0,0,0);
      o[1][1] = __builtin_amdgcn_mfma_f32_32x32x16_bf16(ef1, vb[s][1], o[1][1], 0,0,0);
    }
    __builtin_amdgcn_s_setprio(0);
  };

  const int NT = S_/128;   // 16
  STAGE(0, 0); STAGE(1, 1);

  f32x16 eA0, eA1, eB0, eB1;
  u32 wA0[4][2], wA1[4][2], wB0[4][2], wB1[4][2];

  #pragma unroll 1
  for (int t=0; t<NT; ++t){
    if (t < NT-1) { asm volatile("s_waitcnt vmcnt(8)" ::: "memory"); }
    else          { asm volatile("s_waitcnt vmcnt(0)" ::: "memory"); }
    __builtin_amdgcn_s_barrier();
    asm volatile("" ::: "memory");
    const unsigned char* K_ = sm + (t&1)*32768;
    const unsigned char* V_ = K_ + 16384;

    QK(K_, 0, eA0, eA1);               // 16 QK MFMAs up front (one setprio stretch)
    QK(K_, 1, eB0, eB1);
    PACK(eA0, wA0, p4a[0]);
    PACK(eA1, wA1, p4a[1]);
    PVF(V_, 0, wA0, wA1);
    PACK(eB0, wB0, p4b[0]);
    PACK(eB1, wB1, p4b[1]);
    PVF(V_, 1, wB0, wB1);

    asm volatile("" ::: "memory");
    __builtin_amdgcn_s_barrier();      // everyone done reading buf[t&1]
    asm volatile("" ::: "memory");
    if (t+2 < NT) STAGE(t&1, t+2);
  }

  // ---- cross-wave (key-half) reduce via LDS, then L4 scale + store ----
  float p4f[2];
  #pragma unroll
  for (int f=0;f<2;++f) p4f[f] = p4a[f].x + p4a[f].y + p4b[f].x + p4b[f].y;

  __syncthreads();
  float* red  = (float*)smc;            // [qi][f][ds][lane][16] = 32KB
  float* redp = (float*)(smc + 32768);  // [qi][f][lane] = 1KB
  if (kj==1){
    #pragma unroll
    for (int f=0;f<2;++f){
      #pragma unroll
      for (int ds=0;ds<2;++ds){
        float* dst = red + ((((qi*2+f)*2+ds)*64 + lane)*16);
        #pragma unroll
        for (int r4=0;r4<4;++r4)
          *(float4*)(dst + r4*4) = make_float4(o[f][ds][r4*4],o[f][ds][r4*4+1],o[f][ds][r4*4+2],o[f][ds][r4*4+3]);
      }
      redp[(qi*2+f)*64 + lane] = p4f[f];
    }
  }
  __syncthreads();
  if (kj==0){
    #pragma unroll
    for (int f=0;f<2;++f){
      #pragma unroll
      for (int ds=0;ds<2;++ds){
        const float* srcp = red + ((((qi*2+f)*2+ds)*64 + lane)*16);
        #pragma unroll
        for (int r4=0;r4<4;++r4){
          float4 t = *(const float4*)(srcp + r4*4);
          o[f][ds][r4*4]+=t.x; o[f][ds][r4*4+1]+=t.y; o[f][ds][r4*4+2]+=t.z; o[f][ds][r4*4+3]+=t.w;
        }
      }
      p4f[f] += redp[(qi*2+f)*64 + lane];
      p4f[f] += __shfl_xor(p4f[f], 32);
    }
    float sc0 = GAMMA * rsqrtf(sqrtf(p4f[0]));
    float sc1 = GAMMA * rsqrtf(sqrtf(p4f[1]));
    #pragma unroll
    for (int f=0;f<2;++f){
      #pragma unroll
      for (int r=0;r<16;++r){
        int qrow = (r&3) + 8*(r>>2) + 4*hi;
        float scr = __shfl(f==0 ? sc0 : sc1, qrow);
        size_t n = (size_t)b*S_ + q0 + f*32 + qrow;
        u16* dst = ao + n*E_ + h*HD_;
        dst[l31]    = f2bf(o[f][0][r] * scr);
        dst[32+l31] = f2bf(o[f][1][r] * scr);
      }
    }
  }
}

// ---------------- K3/K5: 128x64-tile bf16 GEMM (y = A @ Bw^T), T3/T4 pipeline ----------------
template<int MODE>
__global__ __launch_bounds__(256, 2) void k_gemm(
    const u16* __restrict__ A, const u16* __restrict__ Bw,
    const float* __restrict__ bias, const float* __restrict__ auxf,
    const u16* __restrict__ aux16, float* __restrict__ out32, u16* __restrict__ out16)
{
  __shared__ alignas(128) unsigned char sm[73728];   // 3 x (A 16KB + B 8KB)
  char* smc = (char*)sm;
  int tid = threadIdx.x, lane = tid&63, wv = tid>>6;
  int l31 = lane&31, hi = lane>>5;
  int wr = wv>>1, wc = wv&1;
  int LL = (blockIdx.x & 7)*64 + (blockIdx.x >> 3);   // 512 = 8 XCD x 64
  int mt = LL >> 4, nt = LL & 15;
  int m0 = mt*128, n0 = nt*64;

  int ric  = lane>>3;
  int colb = ((lane&7)*16) ^ ((ric&7)<<4);
  const char* aSrc[4]; const char* bSrc[2];
  #pragma unroll
  for (int j=0;j<4;++j)
    aSrc[j] = (const char*)A  + ((size_t)(m0 + wv*32 + 8*j + ric)*E_)*2 + colb;
  #pragma unroll
  for (int j=0;j<2;++j)
    bSrc[j] = (const char*)Bw + ((size_t)(n0 + wv*16 + 8*j + ric)*E_)*2 + colb;

  auto STAGE = [&](int bsel, int t){
    char* db = smc + bsel*24576;
    size_t kb2 = (size_t)t*128;
    #pragma unroll
    for (int j=0;j<4;++j) gl_lds16(aSrc[j] + kb2, db + (wv*4+j)*1024);
    #pragma unroll
    for (int j=0;j<2;++j) gl_lds16(bSrc[j] + kb2, db + 16384 + (wv*2+j)*1024);
  };

  f32x16 acc[2] = {{}, {}};

  const int NK = E_/64;   // 16
  STAGE(0, 0); STAGE(1, 1);

  #pragma unroll 1
  for (int t=0; t<NK; ++t){
    if (t < NK-1) { asm volatile("s_waitcnt vmcnt(6)" ::: "memory"); }
    else          { asm volatile("s_waitcnt vmcnt(0)" ::: "memory"); }
    __builtin_amdgcn_s_barrier();
    asm volatile("" ::: "memory");
    if (t+2 < NK) STAGE((t+2)%3, t+2);

    const unsigned char* Ap_ = sm + (t%3)*24576;
    const unsigned char* Bp_ = Ap_ + 16384;
    #pragma unroll
    for (int kk=0;kk<4;++kk){
      bf16x8 bfr = ldfrag(Bp_, wc*32 + l31, kk*32 + hi*16);
      bf16x8 af0 = ldfrag(Ap_, wr*64 + l31,      kk*32 + hi*16);
      bf16x8 af1 = ldfrag(Ap_, wr*64 + 32 + l31, kk*32 + hi*16);
      __builtin_amdgcn_s_setprio(1);
      acc[0] = __builtin_amdgcn_mfma_f32_32x32x16_bf16(af0, bfr, acc[0], 0,0,0);
      acc[1] = __builtin_amdgcn_mfma_f32_32x32x16_bf16(af1, bfr, acc[1], 0,0,0);
      __builtin_amdgcn_s_setprio(0);
    }
  }

  int col = n0 + wc*32 + l31;
  float bi = bias[col];
  #pragma unroll
  for (int rg=0;rg<2;++rg)
    #pragma unroll
    for (int r=0;r<16;++r){
      int mrow = m0 + wr*64 + rg*32 + (r&3) + 8*(r>>2) + 4*hi;
      size_t idx = (size_t)mrow*E_ + col;
      float v = acc[rg][r] + bi;
      if (MODE == 0){
        out16[idx] = f2bf(v + auxf[idx]);
      } else {
        float gg = 1.f/(1.f + __expf(-v));
        out32[idx] = bf2f(aux16[idx]) * gg;
      }
    }
}

// ---------------- K4: LayerNorm over embed dim; bf16 in -> bf16 out ----------------
__global__ __launch_bounds__(256) void k_ln(
    const u16* __restrict__ xin, const float* __restrict__ lnw, const float* __restrict__ lnb,
    u16* __restrict__ xout)
{
  __shared__ float red[8];
  __shared__ float stats[2];
  int row = blockIdx.x, tid = threadIdx.x;
  ushort4 xr = reinterpret_cast<const ushort4*>(xin + (size_t)row*E_)[tid];
  float x0 = bf2f(xr.x), x1 = bf2f(xr.y), x2 = bf2f(xr.z), x3 = bf2f(xr.w);
  float s  = x0 + x1 + x2 + x3;
  float s2 = x0*x0 + x1*x1 + x2*x2 + x3*x3;
  #pragma unroll
  for (int m=1;m<64;m<<=1){ s += __shfl_xor(s,m); s2 += __shfl_xor(s2,m); }
  if ((tid&63)==0){ red[tid>>6] = s; red[4+(tid>>6)] = s2; }
  __syncthreads();
  if (tid==0){
    float ts  = red[0]+red[1]+red[2]+red[3];
    float ts2 = red[4]+red[5]+red[6]+red[7];
    float mu  = ts * (1.f/E_);
    float var = ts2 * (1.f/E_) - mu*mu;
    stats[0] = mu; stats[1] = rsqrtf(var + 1e-5f);
  }
  __syncthreads();
  float mu = stats[0], rstd = stats[1];
  float4 w  = reinterpret_cast<const float4*>(lnw)[tid];
  float4 bb = reinterpret_cast<const float4*>(lnb)[tid];
  ushort4 p;
  p.x = f2bf((x0-mu)*rstd*w.x + bb.x);
  p.y = f2bf((x1-mu)*rstd*w.y + bb.y);
  p.z = f2bf((x2-mu)*rstd*w.z + bb.z);
  p.w = f2bf((x3-mu)*rstd*w.w + bb.w);
  reinterpret_cast<ushort4*>(xout + (size_t)row*E_)[tid] = p;
}

// ---------------- host launch ----------------
extern "C" void kernel_launch(void* const* d_in, const int* in_sizes, int n_in,
                              void* d_out, int out_size, void* d_ws, size_t ws_size,
                              hipStream_t stream)
{
  const float* value = (const float*)d_in[0];
  const float* key   = (const float*)d_in[1];
  const float* query = (const float*)d_in[2];
  const float* Wq    = (const float*)d_in[3];
  const float* Wk    = (const float*)d_in[4];
  const float* Wv    = (const float*)d_in[5];
  const float* Wo    = (const float*)d_in[6];
  const float* bo    = (const float*)d_in[7];
  const float* lnw   = (const float*)d_in[8];
  const float* lnb   = (const float*)d_in[9];
  const float* Wsq   = (const float*)d_in[10];
  const float* bsq   = (const float*)d_in[11];
  float* out = (float*)d_out;

  char* ws = (char*)d_ws;
  const size_t MB = 1ull<<20;
  u16*   qp     = (u16*)(ws + 0*MB);    // K1->K2
  u16*   kp     = (u16*)(ws + 8*MB);    // K1->K2
  u16*   vnT    = (u16*)(ws + 16*MB);   // K1->K2
  u16*   ao     = (u16*)(ws + 24*MB);   // K2->K3 (8MB)
  u16*   xres16 = (u16*)(ws + 8*MB);    // K3->K4 (8MB, over kp)
  u16*   x16    = (u16*)(ws + 16*MB);   // K4->K5 (8MB, over vnT)
  u16*   wo16   = (u16*)(ws + 48*MB);
  u16*   wsq16  = (u16*)(ws + 50*MB);

  k_proj<<<dim3(N_/64, H_+2), 256, 0, stream>>>(query, key, value, Wq, Wk, Wv,
                                                qp, kp, vnT, Wo, Wsq, wo16, wsq16);
  k_attn<<<512, 256, 0, stream>>>(qp, kp, vnT, ao);
  k_gemm<0><<<512, 256, 0, stream>>>(ao, wo16, bo, query, (const u16*)nullptr, (float*)nullptr, xres16);
  k_ln  <<<N_, 256, 0, stream>>>(xres16, lnw, lnb, x16);
  k_gemm<1><<<512, 256, 0, stream>>>(x16, wsq16, bsq, (const float*)nullptr, x16, out, (u16*)nullptr);
}